// Round 2
// baseline (14519.217 us; speedup 1.0000x reference)
//
#include <hip/hip_runtime.h>
#include <cmath>

#define D_MODEL 256
#define NHEADS 8
#define BSZ 8
#define S_TOT 4725
#define NQRY 3600
#define CH 9600   // chunk rows

// ---------------------------------------------------------------------------
// Generic GEMM: C[M,N] = act(A[M,K] @ W[N,K]^T + bias[N]); K % 16 == 0
// ---------------------------------------------------------------------------
__global__ __launch_bounds__(256) void gemm_kernel(
    const float* __restrict__ A, const float* __restrict__ W,
    const float* __restrict__ bias, float* __restrict__ C,
    int M, int N, int K, int relu)
{
    __shared__ float As[16][65];
    __shared__ float Ws[16][65];
    const int tx = threadIdx.x & 15;
    const int ty = threadIdx.x >> 4;
    const int bm = blockIdx.x * 64;
    const int bn = blockIdx.y * 64;
    float acc[4][4] = {};
    for (int k0 = 0; k0 < K; k0 += 16) {
#pragma unroll
        for (int i = 0; i < 4; i++) {
            int idx = threadIdx.x + i * 256;
            int m = idx >> 4, kk = idx & 15;
            int gm = bm + m;
            As[kk][m] = (gm < M) ? A[(size_t)gm * K + k0 + kk] : 0.f;
        }
#pragma unroll
        for (int i = 0; i < 4; i++) {
            int idx = threadIdx.x + i * 256;
            int n = idx >> 4, kk = idx & 15;
            int gn = bn + n;
            Ws[kk][n] = (gn < N) ? W[(size_t)gn * K + k0 + kk] : 0.f;
        }
        __syncthreads();
#pragma unroll
        for (int kk = 0; kk < 16; kk++) {
            float a[4], w[4];
#pragma unroll
            for (int i = 0; i < 4; i++) a[i] = As[kk][ty * 4 + i];
#pragma unroll
            for (int j = 0; j < 4; j++) w[j] = Ws[kk][tx * 4 + j];
#pragma unroll
            for (int i = 0; i < 4; i++)
#pragma unroll
                for (int j = 0; j < 4; j++)
                    acc[i][j] = fmaf(a[i], w[j], acc[i][j]);
        }
        __syncthreads();
    }
#pragma unroll
    for (int i = 0; i < 4; i++) {
        int gm = bm + ty * 4 + i;
        if (gm >= M) continue;
#pragma unroll
        for (int j = 0; j < 4; j++) {
            int gn = bn + tx * 4 + j;
            if (gn >= N) continue;
            float v = acc[i][j] + bias[gn];
            if (relu) v = fmaxf(v, 0.f);
            C[(size_t)gm * N + gn] = v;
        }
    }
}

__device__ __forceinline__ void level_of(int s, int& l, int& H, int& W, int& hw)
{
    if (s < 3600)      { l = 0; H = 60; W = 60; hw = s; }
    else if (s < 4500) { l = 1; H = 30; W = 30; hw = s - 3600; }
    else               { l = 2; H = 15; W = 15; hw = s - 4500; }
}

// src[b, s, d] = feat_l[b, d, y, x]
__global__ void build_src_kernel(const float* __restrict__ f0, const float* __restrict__ f1,
                                 const float* __restrict__ f2, float* __restrict__ X)
{
    int t = blockIdx.x * blockDim.x + threadIdx.x;
    if (t >= BSZ * S_TOT * D_MODEL) return;
    int d = t & 255;
    int r = t >> 8;
    int s = r % S_TOT;
    int b = r / S_TOT;
    int l, H, W, hw; level_of(s, l, H, W, hw);
    const float* f = (l == 0) ? f0 : (l == 1) ? f1 : f2;
    X[t] = f[((size_t)b * D_MODEL + d) * (size_t)(H * W) + hw];
}

// pos[s, d] = sine pos embed + level_embed[l, d]
__global__ void build_pos_kernel(const float* __restrict__ level_embed, float* __restrict__ pos)
{
    int t = blockIdx.x * blockDim.x + threadIdx.x;
    if (t >= S_TOT * D_MODEL) return;
    int d = t & 255;
    int s = t >> 8;
    int l, H, W, hw; level_of(s, l, H, W, hw);
    int y = hw / W, x = hw % W;
    int dd = (d < 128) ? d : d - 128;
    float v = (d < 128)
        ? ((float)(y + 1)) / ((float)H + 1e-6f) * 6.28318530717958647692f
        : ((float)(x + 1)) / ((float)W + 1e-6f) * 6.28318530717958647692f;
    float tpow = powf(10000.f, (float)(2 * (dd >> 1)) * (1.f / 128.f));
    float arg = v / tpow;
    float val = (dd & 1) ? cosf(arg) : sinf(arg);
    pos[t] = val + level_embed[l * D_MODEL + d];
}

__global__ void build_ref_kernel(float* __restrict__ refE, float* __restrict__ refD)
{
    int t = blockIdx.x * blockDim.x + threadIdx.x;
    if (t < S_TOT) {
        int l, H, W, hw; level_of(t, l, H, W, hw);
        int y = hw / W, x = hw % W;
        refE[2 * t]     = ((float)x + 0.5f) / (float)W;
        refE[2 * t + 1] = ((float)y + 0.5f) / (float)H;
    } else if (t < S_TOT + NQRY) {
        int q = t - S_TOT;
        int y = q / 60, x = q % 60;
        refD[2 * q]     = ((float)x + 0.5f) / 60.f;
        refD[2 * q + 1] = ((float)y + 0.5f) / 60.f;
    }
}

// tgt[nq, b, d] = context + query_embed[nq, d]
__global__ void build_tgt_kernel(const float* __restrict__ context, const float* __restrict__ qe,
                                 float* __restrict__ TGT)
{
    int t = blockIdx.x * blockDim.x + threadIdx.x;
    if (t >= NQRY * BSZ * D_MODEL) return;
    int d = t & 255;
    int nq = t >> 11;   // / (BSZ*D_MODEL)
    TGT[t] = context[t] + qe[nq * D_MODEL + d];
}

// Q_chunk[i] = X[r0+row, d] + pos[(r0+row)%S_TOT, d]
__global__ void add_pos_chunk_kernel(const float* __restrict__ X, const float* __restrict__ pos,
                                     float* __restrict__ Q, int r0, int rows)
{
    int t = blockIdx.x * blockDim.x + threadIdx.x;
    if (t >= rows * D_MODEL) return;
    int d = t & 255;
    int m = r0 + (t >> 8);
    int s = m % S_TOT;
    Q[t] = X[(size_t)m * D_MODEL + d] + pos[(size_t)s * D_MODEL + d];
}

// softmax over 12 logits per (row, head); aw chunk layout [rows, 96]
__global__ void aw_softmax_kernel(float* __restrict__ aw, int cnt)
{
    int t = blockIdx.x * blockDim.x + threadIdx.x;
    if (t >= cnt) return;
    float* p = aw + (size_t)t * 12;
    float e[12];
    float mx = p[0];
#pragma unroll
    for (int i = 1; i < 12; i++) mx = fmaxf(mx, p[i]);
    float s = 0.f;
#pragma unroll
    for (int i = 0; i < 12; i++) { e[i] = expf(p[i] - mx); s += e[i]; }
    float inv = 1.f / s;
#pragma unroll
    for (int i = 0; i < 12; i++) p[i] = e[i] * inv;
}

// MSDeformAttn sampling, chunked. value [BSZ,S_TOT,256]; off/aw/out are chunk-local.
// global row m = m0 + blockIdx.x; b = m/Lq, q = m%Lq. One block per row.
__global__ void msda_kernel(const float* __restrict__ value, const float* __restrict__ off,
                            const float* __restrict__ aw, const float* __restrict__ ref,
                            float* __restrict__ out, int Lq, int m0)
{
    int lm = blockIdx.x;
    int m = m0 + lm;
    int h = threadIdx.x >> 5;
    int ch = threadIdx.x & 31;
    int b = m / Lq, q = m - b * Lq;
    float rx = ref[2 * q], ry = ref[2 * q + 1];
    const float* offp = off + (size_t)lm * 192 + h * 24;
    const float* awp  = aw  + (size_t)lm * 96  + h * 12;
    float acc = 0.f;
    const int HWs[3][3] = {{60, 60, 0}, {30, 30, 3600}, {15, 15, 4500}};
#pragma unroll
    for (int l = 0; l < 3; l++) {
        int H = HWs[l][0], W = HWs[l][1], s0 = HWs[l][2];
        const float* vbase = value + ((size_t)b * S_TOT + s0) * 256 + h * 32 + ch;
#pragma unroll
        for (int p = 0; p < 4; p++) {
            float ox = offp[(l * 4 + p) * 2];
            float oy = offp[(l * 4 + p) * 2 + 1];
            float w  = awp[l * 4 + p];
            float lx = rx * W + ox - 0.5f;
            float ly = ry * H + oy - 0.5f;
            float x0f = floorf(lx), y0f = floorf(ly);
            int x0 = (int)x0f, y0 = (int)y0f;
            float wx1 = lx - x0f, wy1 = ly - y0f;
            float wx0 = 1.f - wx1, wy0 = 1.f - wy1;
            float s = 0.f;
#pragma unroll
            for (int dy = 0; dy < 2; dy++)
#pragma unroll
                for (int dx = 0; dx < 2; dx++) {
                    int xi = x0 + dx, yi = y0 + dy;
                    if (xi >= 0 && xi < W && yi >= 0 && yi < H) {
                        float cw = (dx ? wx1 : wx0) * (dy ? wy1 : wy0);
                        s += cw * vbase[(size_t)(yi * W + xi) * 256];
                    }
                }
            acc += w * s;
        }
    }
    out[(size_t)lm * 256 + h * 32 + ch] = acc;
}

// out = LayerNorm(x + a) * g + b ; one wave per 256-wide row; in-place safe
__global__ void ln_res_kernel(const float* __restrict__ x, const float* __restrict__ a,
                              const float* __restrict__ g, const float* __restrict__ b,
                              float* __restrict__ out, int M)
{
    int wave = threadIdx.x >> 6;
    int lane = threadIdx.x & 63;
    int row = blockIdx.x * 4 + wave;
    if (row >= M) return;
    const float* xp = x + (size_t)row * 256;
    const float* ap = a + (size_t)row * 256;
    float v[4];
    float s = 0.f;
#pragma unroll
    for (int i = 0; i < 4; i++) { v[i] = xp[lane + i * 64] + ap[lane + i * 64]; s += v[i]; }
#pragma unroll
    for (int o = 32; o > 0; o >>= 1) s += __shfl_down(s, o);
    s = __shfl(s, 0);
    float mean = s * (1.f / 256.f);
    float vs = 0.f;
#pragma unroll
    for (int i = 0; i < 4; i++) { float d = v[i] - mean; vs += d * d; }
#pragma unroll
    for (int o = 32; o > 0; o >>= 1) vs += __shfl_down(vs, o);
    vs = __shfl(vs, 0);
    float inv = rsqrtf(vs * (1.f / 256.f) + 1e-5f);
    float* op = out + (size_t)row * 256;
#pragma unroll
    for (int i = 0; i < 4; i++) {
        int d = lane + i * 64;
        op[d] = (v[i] - mean) * inv * g[d] + b[d];
    }
}

// Decoder self-attention over L=8 (batch dim). Chunk covers nCnt query indices;
// qkv chunk rows r = n_local*8 + l (q @0, k @256, v @512); o chunk same rows.
__global__ void mha_kernel(const float* __restrict__ qkv, float* __restrict__ o, int nCnt)
{
    int t = blockIdx.x * blockDim.x + threadIdx.x;
    if (t >= nCnt * 64) return;
    int l = t & 7;
    int h = (t >> 3) & 7;
    int n = t >> 6;
    const float* qp = qkv + (size_t)(n * 8 + l) * 768 + h * 32;
    float q[32];
#pragma unroll
    for (int d = 0; d < 32; d++) q[d] = qp[d];
    float sc[8];
#pragma unroll
    for (int s = 0; s < 8; s++) {
        const float* kp = qkv + (size_t)(n * 8 + s) * 768 + 256 + h * 32;
        float acc = 0.f;
#pragma unroll
        for (int d = 0; d < 32; d++) acc = fmaf(q[d], kp[d], acc);
        sc[s] = acc * 0.17677669529663688f;   // 1/sqrt(32)
    }
    float mx = sc[0];
#pragma unroll
    for (int s = 1; s < 8; s++) mx = fmaxf(mx, sc[s]);
    float sum = 0.f;
#pragma unroll
    for (int s = 0; s < 8; s++) { sc[s] = expf(sc[s] - mx); sum += sc[s]; }
    float inv = 1.f / sum;
    float outv[32] = {};
#pragma unroll
    for (int s = 0; s < 8; s++) {
        const float* vp = qkv + (size_t)(n * 8 + s) * 768 + 512 + h * 32;
        float a = sc[s] * inv;
#pragma unroll
        for (int d = 0; d < 32; d++) outv[d] = fmaf(a, vp[d], outv[d]);
    }
    float* op = o + (size_t)(n * 8 + l) * 256 + h * 32;
#pragma unroll
    for (int d = 0; d < 32; d++) op[d] = outv[d];
}

// [NQ,BS,D] -> [BS,NQ,D]
__global__ void transp_nb_to_bn_kernel(const float* __restrict__ src, float* __restrict__ dst)
{
    int t = blockIdx.x * blockDim.x + threadIdx.x;
    if (t >= NQRY * BSZ * D_MODEL) return;
    int d = t & 255; int r = t >> 8; int b = r & 7; int nq = r >> 3;
    dst[((size_t)b * NQRY + nq) * D_MODEL + d] = src[t];
}

// [BS,NQ,D] -> [NQ,BS,D]
__global__ void transp_bn_to_nb_kernel(const float* __restrict__ src, float* __restrict__ dst)
{
    int t = blockIdx.x * blockDim.x + threadIdx.x;
    if (t >= NQRY * BSZ * D_MODEL) return;
    int d = t & 255; int r = t >> 8; int nq = r % NQRY; int b = r / NQRY;
    dst[((size_t)nq * BSZ + b) * D_MODEL + d] = src[t];
}

__global__ void copy_kernel(const float* __restrict__ src, float* __restrict__ dst, int n)
{
    int t = blockIdx.x * blockDim.x + threadIdx.x;
    if (t < n) dst[t] = src[t];
}

// ---------------------------------------------------------------------------
static inline void gemm(const float* A, const float* W, const float* b, float* C,
                        int M, int N, int K, int relu, hipStream_t s)
{
    dim3 g((M + 63) / 64, (N + 63) / 64);
    hipLaunchKernelGGL(gemm_kernel, g, dim3(256), 0, s, A, W, b, C, M, N, K, relu);
}

extern "C" void kernel_launch(void* const* d_in, const int* in_sizes, int n_in,
                              void* d_out, int out_size, void* d_ws, size_t ws_size,
                              hipStream_t stream)
{
    const float* feat0       = (const float*)d_in[0];
    const float* feat1       = (const float*)d_in[1];
    const float* feat2       = (const float*)d_in[2];
    const float* context     = (const float*)d_in[3];
    const float* query_embed = (const float*)d_in[4];
    const float* level_embed = (const float*)d_in[5];
    const float* enc_off_W = (const float*)d_in[6];
    const float* enc_off_b = (const float*)d_in[7];
    const float* enc_aw_W  = (const float*)d_in[8];
    const float* enc_aw_b  = (const float*)d_in[9];
    const float* enc_vp_W  = (const float*)d_in[10];
    const float* enc_vp_b  = (const float*)d_in[11];
    const float* enc_op_W  = (const float*)d_in[12];
    const float* enc_op_b  = (const float*)d_in[13];
    const float* enc_fc1_W = (const float*)d_in[14];
    const float* enc_fc1_b = (const float*)d_in[15];
    const float* enc_fc2_W = (const float*)d_in[16];
    const float* enc_fc2_b = (const float*)d_in[17];
    const float* enc_ln1_g = (const float*)d_in[18];
    const float* enc_ln1_b = (const float*)d_in[19];
    const float* enc_ln2_g = (const float*)d_in[20];
    const float* enc_ln2_b = (const float*)d_in[21];
    const float* dec_off_W = (const float*)d_in[22];
    const float* dec_off_b = (const float*)d_in[23];
    const float* dec_aw_W  = (const float*)d_in[24];
    const float* dec_aw_b  = (const float*)d_in[25];
    const float* dec_vp_W  = (const float*)d_in[26];
    const float* dec_vp_b  = (const float*)d_in[27];
    const float* dec_op_W  = (const float*)d_in[28];
    const float* dec_op_b  = (const float*)d_in[29];
    const float* dec_fc1_W = (const float*)d_in[30];
    const float* dec_fc1_b = (const float*)d_in[31];
    const float* dec_fc2_W = (const float*)d_in[32];
    const float* dec_fc2_b = (const float*)d_in[33];
    const float* dec_ln1_g = (const float*)d_in[34];
    const float* dec_ln1_b = (const float*)d_in[35];
    const float* dec_ln2_g = (const float*)d_in[36];
    const float* dec_ln2_b = (const float*)d_in[37];
    const float* sa_in_W   = (const float*)d_in[38];
    const float* sa_in_b   = (const float*)d_in[39];
    const float* sa_out_W  = (const float*)d_in[40];
    const float* sa_out_b  = (const float*)d_in[41];
    const float* dec_ln3_g = (const float*)d_in[42];
    const float* dec_ln3_b = (const float*)d_in[43];

    const int ME = BSZ * S_TOT;   // 37800 encoder rows
    const int MD = BSZ * NQRY;    // 28800 decoder rows
    const int EW = ME * D_MODEL;  // 9,676,800
    const int DW = MD * D_MODEL;  // 7,372,800

    // ---- workspace layout (floats), ~181.6 MiB total ----
    float* ws = (float*)d_ws;
    size_t o = 0;
    float* Xb   = ws + o; o += (size_t)EW;            // activations -> memory
    float* Vb   = ws + o; o += (size_t)EW;            // value projection
    float* TGTb = ws + o; o += (size_t)DW;            // tgt [NQ,BS,D]
    float* TQb  = ws + o; o += (size_t)DW;            // tgt [BS,NQ,D]
    float* SCR  = ws + o; o += (size_t)12288000;      // time-multiplexed chunk scratch
    float* POSb = ws + o; o += (size_t)S_TOT * D_MODEL;
    float* REFEb = ws + o; o += 9472;
    float* REFDb = ws + o; o += 7232;
    if (ws_size < o * sizeof(float)) return;          // refuse to fault

    // SCR sub-regions (float offsets) — lifetimes are phase-disjoint per chunk
    float* OFFc = SCR;              // [CH,192]  = 1,843,200
    float* AWc  = SCR + 1843200;    // [CH,96]   =   921,600
    float* Qc   = SCR + 2764800;    // [CH,256]  = 2,457,600 (enc q; dec msda-out)
    float* OUTc = SCR + 5222400;    // [CH,256]  (enc msda-out; dec op-out)
    float* Yc   = SCR + 7680000;    // [CH,256]  (enc op-out)
    float* HIDc = SCR;              // [CH,1024] = 9,830,400 (FFN hidden)
    float* Y2c  = SCR + 9830400;    // [CH,256]  (FFN out / dec self-attn out)
    float* QKVc = SCR;              // [CH,768]  = 7,372,800 (dec self-attn)
    float* SOc  = SCR + 7372800;    // [CH/8*8,256] mha out (2,457,600)

    // ---- setup ----
    hipLaunchKernelGGL(build_pos_kernel, dim3((S_TOT * D_MODEL + 255) / 256), dim3(256), 0, stream,
                       level_embed, POSb);
    hipLaunchKernelGGL(build_ref_kernel, dim3((S_TOT + NQRY + 255) / 256), dim3(256), 0, stream,
                       REFEb, REFDb);
    hipLaunchKernelGGL(build_src_kernel, dim3((EW + 255) / 256), dim3(256), 0, stream,
                       feat0, feat1, feat2, Xb);
    hipLaunchKernelGGL(build_tgt_kernel, dim3((DW + 255) / 256), dim3(256), 0, stream,
                       context, query_embed, TGTb);

    // ---- encoder ----
    for (int i = 0; i < 3; i++) {
        // value projection over full sequence (needed by every chunk's sampling)
        gemm(Xb, enc_vp_W + (size_t)i * 65536, enc_vp_b + i * 256, Vb, ME, 256, 256, 0, stream);
        for (int r0 = 0; r0 < ME; r0 += CH) {
            int rows = (ME - r0 < CH) ? (ME - r0) : CH;
            hipLaunchKernelGGL(add_pos_chunk_kernel, dim3((rows * 256 + 255) / 256), dim3(256),
                               0, stream, Xb, POSb, Qc, r0, rows);
            gemm(Qc, enc_off_W + (size_t)i * 49152, enc_off_b + i * 192, OFFc, rows, 192, 256, 0, stream);
            gemm(Qc, enc_aw_W + (size_t)i * 24576, enc_aw_b + i * 96, AWc, rows, 96, 256, 0, stream);
            hipLaunchKernelGGL(aw_softmax_kernel, dim3((rows * 8 + 255) / 256), dim3(256), 0, stream,
                               AWc, rows * 8);
            hipLaunchKernelGGL(msda_kernel, dim3(rows), dim3(256), 0, stream,
                               Vb, OFFc, AWc, REFEb, OUTc, S_TOT, r0);
            gemm(OUTc, enc_op_W + (size_t)i * 65536, enc_op_b + i * 256, Yc, rows, 256, 256, 0, stream);
            hipLaunchKernelGGL(ln_res_kernel, dim3((rows + 3) / 4), dim3(256), 0, stream,
                               Xb + (size_t)r0 * 256, Yc, enc_ln1_g + i * 256, enc_ln1_b + i * 256,
                               Xb + (size_t)r0 * 256, rows);
            gemm(Xb + (size_t)r0 * 256, enc_fc1_W + (size_t)i * 262144, enc_fc1_b + i * 1024,
                 HIDc, rows, 1024, 256, 1, stream);
            gemm(HIDc, enc_fc2_W + (size_t)i * 262144, enc_fc2_b + i * 256, Y2c, rows, 256, 1024, 0, stream);
            hipLaunchKernelGGL(ln_res_kernel, dim3((rows + 3) / 4), dim3(256), 0, stream,
                               Xb + (size_t)r0 * 256, Y2c, enc_ln2_g + i * 256, enc_ln2_b + i * 256,
                               Xb + (size_t)r0 * 256, rows);
        }
    }
    // Xb now holds `memory`.

    // ---- decoder ----
    for (int i = 0; i < 3; i++) {
        // self-attention (L=8 over batch dim), chunked over query groups
        for (int c = 0; c < 3; c++) {
            size_t r0 = (size_t)c * CH;          // rows = 9600, n in [c*1200, c*1200+1200)
            gemm(TGTb + r0 * 256, sa_in_W + (size_t)i * 196608, sa_in_b + i * 768,
                 QKVc, CH, 768, 256, 0, stream);
            hipLaunchKernelGGL(mha_kernel, dim3((1200 * 64 + 255) / 256), dim3(256), 0, stream,
                               QKVc, SOc, 1200);
            gemm(SOc, sa_out_W + (size_t)i * 65536, sa_out_b + i * 256, Y2c, CH, 256, 256, 0, stream);
            hipLaunchKernelGGL(ln_res_kernel, dim3((CH + 3) / 4), dim3(256), 0, stream,
                               TGTb + r0 * 256, Y2c, dec_ln2_g + i * 256, dec_ln2_b + i * 256,
                               TGTb + r0 * 256, CH);
        }
        hipLaunchKernelGGL(transp_nb_to_bn_kernel, dim3((DW + 255) / 256), dim3(256), 0, stream,
                           TGTb, TQb);
        // MSDA over memory
        gemm(Xb, dec_vp_W + (size_t)i * 65536, dec_vp_b + i * 256, Vb, ME, 256, 256, 0, stream);
        for (int c = 0; c < 3; c++) {
            size_t r0 = (size_t)c * CH;
            gemm(TQb + r0 * 256, dec_off_W + (size_t)i * 49152, dec_off_b + i * 192,
                 OFFc, CH, 192, 256, 0, stream);
            gemm(TQb + r0 * 256, dec_aw_W + (size_t)i * 24576, dec_aw_b + i * 96,
                 AWc, CH, 96, 256, 0, stream);
            hipLaunchKernelGGL(aw_softmax_kernel, dim3((CH * 8 + 255) / 256), dim3(256), 0, stream,
                               AWc, CH * 8);
            hipLaunchKernelGGL(msda_kernel, dim3(CH), dim3(256), 0, stream,
                               Vb, OFFc, AWc, REFDb, Qc, NQRY, (int)r0);
            gemm(Qc, dec_op_W + (size_t)i * 65536, dec_op_b + i * 256, OUTc, CH, 256, 256, 0, stream);
            hipLaunchKernelGGL(ln_res_kernel, dim3((CH + 3) / 4), dim3(256), 0, stream,
                               TQb + r0 * 256, OUTc, dec_ln1_g + i * 256, dec_ln1_b + i * 256,
                               TQb + r0 * 256, CH);
            gemm(TQb + r0 * 256, dec_fc1_W + (size_t)i * 262144, dec_fc1_b + i * 1024,
                 HIDc, CH, 1024, 256, 1, stream);
            gemm(HIDc, dec_fc2_W + (size_t)i * 262144, dec_fc2_b + i * 256, Y2c, CH, 256, 1024, 0, stream);
            hipLaunchKernelGGL(ln_res_kernel, dim3((CH + 3) / 4), dim3(256), 0, stream,
                               TQb + r0 * 256, Y2c, dec_ln3_g + i * 256, dec_ln3_b + i * 256,
                               TQb + r0 * 256, CH);
        }
        hipLaunchKernelGGL(transp_bn_to_nb_kernel, dim3((DW + 255) / 256), dim3(256), 0, stream,
                           TQb, TGTb);
    }

    hipLaunchKernelGGL(copy_kernel, dim3((DW + 255) / 256), dim3(256), 0, stream,
                       TGTb, (float*)d_out, DW);
}

// Round 3
// 4953.085 us; speedup vs baseline: 2.9313x; 2.9313x over previous
//
#include <hip/hip_runtime.h>
#include <cmath>

#define D_MODEL 256
#define NHEADS 8
#define BSZ 8
#define S_TOT 4725
#define NQRY 3600
#define CH 9600   // chunk rows

typedef unsigned short ushortT;
using bf16x8  = __attribute__((ext_vector_type(8))) __bf16;
using floatx4 = __attribute__((ext_vector_type(4))) float;

__device__ __forceinline__ ushortT f2bf(float f)
{
    union { float f; unsigned u; } v; v.f = f;
    unsigned r = v.u + 0x7FFFu + ((v.u >> 16) & 1u);
    return (ushortT)(r >> 16);
}
__device__ __forceinline__ float bf2f(ushortT u)
{
    union { unsigned u; float f; } v; v.u = ((unsigned)u) << 16;
    return v.f;
}

// ---------------------------------------------------------------------------
// bf16 MFMA GEMM: C[M,N] = act(A[M,K] @ W[N,K]^T + bias[N])
// A,W bf16 (as ushort); C fp32 or bf16. K % 32 == 0. Tile 128x128, BK=32.
// ---------------------------------------------------------------------------
#define LDA 40   // padded LDS row length (bf16 elems): 80B rows -> 2-way-max conflicts

template<int RELU, int OUTBF>
__global__ __launch_bounds__(256) void gemm_bf16_kernel(
    const ushortT* __restrict__ A, const ushortT* __restrict__ W,
    const float* __restrict__ bias, void* __restrict__ Cout,
    int M, int N, int K)
{
    __shared__ ushortT As[128 * LDA];
    __shared__ ushortT Bs[128 * LDA];
    const int tid  = threadIdx.x;
    const int lane = tid & 63;
    const int wid  = tid >> 6;
    const int bm = blockIdx.x * 128;
    const int bn = blockIdx.y * 128;
    const int wm = (wid & 1) * 64;
    const int wn = (wid >> 1) * 64;
    const int col16 = lane & 15;
    const int quad  = lane >> 4;

    floatx4 acc[4][4];
#pragma unroll
    for (int i = 0; i < 4; i++)
#pragma unroll
        for (int j = 0; j < 4; j++) acc[i][j] = (floatx4){0.f, 0.f, 0.f, 0.f};

    for (int k0 = 0; k0 < K; k0 += 32) {
        if (k0) __syncthreads();
#pragma unroll
        for (int r = 0; r < 2; r++) {
            int idx = tid + r * 256;       // 0..511
            int row = idx >> 2;            // 0..127
            int cg  = idx & 3;             // 16B group within 32-elem row
            int gm = bm + row; if (gm >= M) gm = M - 1;
            *(uint4*)&As[row * LDA + cg * 8] =
                *(const uint4*)(A + (size_t)gm * K + k0 + cg * 8);
            int gn = bn + row; if (gn >= N) gn = N - 1;
            *(uint4*)&Bs[row * LDA + cg * 8] =
                *(const uint4*)(W + (size_t)gn * K + k0 + cg * 8);
        }
        __syncthreads();
        bf16x8 av[4], bv[4];
#pragma unroll
        for (int i = 0; i < 4; i++) {
            av[i] = *(const bf16x8*)&As[(wm + i * 16 + col16) * LDA + quad * 8];
            bv[i] = *(const bf16x8*)&Bs[(wn + i * 16 + col16) * LDA + quad * 8];
        }
#pragma unroll
        for (int mi = 0; mi < 4; mi++)
#pragma unroll
            for (int ni = 0; ni < 4; ni++)
                acc[mi][ni] = __builtin_amdgcn_mfma_f32_16x16x32_bf16(
                    av[mi], bv[ni], acc[mi][ni], 0, 0, 0);
    }

    // Epilogue: D row = quad*4+r, col = lane&15
#pragma unroll
    for (int ni = 0; ni < 4; ni++) {
        int gn = bn + wn + ni * 16 + col16;
        if (gn >= N) continue;
        float bs = bias[gn];
#pragma unroll
        for (int mi = 0; mi < 4; mi++) {
#pragma unroll
            for (int r = 0; r < 4; r++) {
                int gm = bm + wm + mi * 16 + quad * 4 + r;
                if (gm >= M) continue;
                float v = acc[mi][ni][r] + bs;
                if (RELU) v = fmaxf(v, 0.f);
                if (OUTBF) ((ushortT*)Cout)[(size_t)gm * N + gn] = f2bf(v);
                else       ((float*)Cout)[(size_t)gm * N + gn] = v;
            }
        }
    }
}

static inline void gemm_bf16(const ushortT* A, const ushortT* W, const float* bias,
                             void* C, int M, int N, int K, int relu, int outbf,
                             hipStream_t s)
{
    dim3 g((M + 127) / 128, (N + 127) / 128);
    if (relu) {
        if (outbf) hipLaunchKernelGGL((gemm_bf16_kernel<1,1>), g, dim3(256), 0, s, A, W, bias, C, M, N, K);
        else       hipLaunchKernelGGL((gemm_bf16_kernel<1,0>), g, dim3(256), 0, s, A, W, bias, C, M, N, K);
    } else {
        if (outbf) hipLaunchKernelGGL((gemm_bf16_kernel<0,1>), g, dim3(256), 0, s, A, W, bias, C, M, N, K);
        else       hipLaunchKernelGGL((gemm_bf16_kernel<0,0>), g, dim3(256), 0, s, A, W, bias, C, M, N, K);
    }
}

// ---------------------------------------------------------------------------
__global__ void f2bf_kernel(const float* __restrict__ src, ushortT* __restrict__ dst, int n)
{
    int t = blockIdx.x * blockDim.x + threadIdx.x;
    if (t < n) dst[t] = f2bf(src[t]);
}

__device__ __forceinline__ void level_of(int s, int& l, int& H, int& W, int& hw)
{
    if (s < 3600)      { l = 0; H = 60; W = 60; hw = s; }
    else if (s < 4500) { l = 1; H = 30; W = 30; hw = s - 3600; }
    else               { l = 2; H = 15; W = 15; hw = s - 4500; }
}

// src[b, s, d] = feat_l[b, d, y, x]; writes fp32 X and bf16 Xh
__global__ void build_src_kernel(const float* __restrict__ f0, const float* __restrict__ f1,
                                 const float* __restrict__ f2, float* __restrict__ X,
                                 ushortT* __restrict__ Xh)
{
    int t = blockIdx.x * blockDim.x + threadIdx.x;
    if (t >= BSZ * S_TOT * D_MODEL) return;
    int d = t & 255;
    int r = t >> 8;
    int s = r % S_TOT;
    int b = r / S_TOT;
    int l, H, W, hw; level_of(s, l, H, W, hw);
    const float* f = (l == 0) ? f0 : (l == 1) ? f1 : f2;
    float v = f[((size_t)b * D_MODEL + d) * (size_t)(H * W) + hw];
    X[t] = v;
    Xh[t] = f2bf(v);
}

__global__ void build_pos_kernel(const float* __restrict__ level_embed, float* __restrict__ pos)
{
    int t = blockIdx.x * blockDim.x + threadIdx.x;
    if (t >= S_TOT * D_MODEL) return;
    int d = t & 255;
    int s = t >> 8;
    int l, H, W, hw; level_of(s, l, H, W, hw);
    int y = hw / W, x = hw % W;
    int dd = (d < 128) ? d : d - 128;
    float v = (d < 128)
        ? ((float)(y + 1)) / ((float)H + 1e-6f) * 6.28318530717958647692f
        : ((float)(x + 1)) / ((float)W + 1e-6f) * 6.28318530717958647692f;
    float tpow = powf(10000.f, (float)(2 * (dd >> 1)) * (1.f / 128.f));
    float arg = v / tpow;
    float val = (dd & 1) ? cosf(arg) : sinf(arg);
    pos[t] = val + level_embed[l * D_MODEL + d];
}

__global__ void build_ref_kernel(float* __restrict__ refE, float* __restrict__ refD)
{
    int t = blockIdx.x * blockDim.x + threadIdx.x;
    if (t < S_TOT) {
        int l, H, W, hw; level_of(t, l, H, W, hw);
        int y = hw / W, x = hw % W;
        refE[2 * t]     = ((float)x + 0.5f) / (float)W;
        refE[2 * t + 1] = ((float)y + 0.5f) / (float)H;
    } else if (t < S_TOT + NQRY) {
        int q = t - S_TOT;
        int y = q / 60, x = q % 60;
        refD[2 * q]     = ((float)x + 0.5f) / 60.f;
        refD[2 * q + 1] = ((float)y + 0.5f) / 60.f;
    }
}

// tgt[nq, b, d] = context + query_embed[nq, d]; fp32 + bf16 mirror
__global__ void build_tgt_kernel(const float* __restrict__ context, const float* __restrict__ qe,
                                 float* __restrict__ TGT, ushortT* __restrict__ TGTh)
{
    int t = blockIdx.x * blockDim.x + threadIdx.x;
    if (t >= NQRY * BSZ * D_MODEL) return;
    int d = t & 255;
    int nq = t >> 11;
    float v = context[t] + qe[nq * D_MODEL + d];
    TGT[t] = v;
    TGTh[t] = f2bf(v);
}

// Qh_chunk = bf16(X[r0+row] + pos[(r0+row)%S_TOT])
__global__ void add_pos_chunk_kernel(const float* __restrict__ X, const float* __restrict__ pos,
                                     ushortT* __restrict__ Qh, int r0, int rows)
{
    int t = blockIdx.x * blockDim.x + threadIdx.x;
    if (t >= rows * D_MODEL) return;
    int d = t & 255;
    int m = r0 + (t >> 8);
    int s = m % S_TOT;
    Qh[t] = f2bf(X[(size_t)m * D_MODEL + d] + pos[(size_t)s * D_MODEL + d]);
}

__global__ void aw_softmax_kernel(float* __restrict__ aw, int cnt)
{
    int t = blockIdx.x * blockDim.x + threadIdx.x;
    if (t >= cnt) return;
    float* p = aw + (size_t)t * 12;
    float e[12];
    float mx = p[0];
#pragma unroll
    for (int i = 1; i < 12; i++) mx = fmaxf(mx, p[i]);
    float s = 0.f;
#pragma unroll
    for (int i = 0; i < 12; i++) { e[i] = expf(p[i] - mx); s += e[i]; }
    float inv = 1.f / s;
#pragma unroll
    for (int i = 0; i < 12; i++) p[i] = e[i] * inv;
}

// MSDA sampling: value bf16 [BSZ,S_TOT,256]; out bf16 chunk.
// mode 0 (enc): b=m/S_TOT, q=m%S_TOT.  mode 1 (dec n-major): q=m>>3, b=m&7.
__global__ void msda_kernel(const ushortT* __restrict__ value, const float* __restrict__ off,
                            const float* __restrict__ aw, const float* __restrict__ ref,
                            ushortT* __restrict__ out, int mode, int m0)
{
    int lm = blockIdx.x;
    int m = m0 + lm;
    int h = threadIdx.x >> 5;
    int ch = threadIdx.x & 31;
    int b, q;
    if (mode == 0) { b = m / S_TOT; q = m - b * S_TOT; }
    else           { q = m >> 3;    b = m & 7; }
    float rx = ref[2 * q], ry = ref[2 * q + 1];
    const float* offp = off + (size_t)lm * 192 + h * 24;
    const float* awp  = aw  + (size_t)lm * 96  + h * 12;
    float acc = 0.f;
    const int HWs[3][3] = {{60, 60, 0}, {30, 30, 3600}, {15, 15, 4500}};
#pragma unroll
    for (int l = 0; l < 3; l++) {
        int H = HWs[l][0], W = HWs[l][1], s0 = HWs[l][2];
        const ushortT* vbase = value + ((size_t)b * S_TOT + s0) * 256 + h * 32 + ch;
#pragma unroll
        for (int p = 0; p < 4; p++) {
            float ox = offp[(l * 4 + p) * 2];
            float oy = offp[(l * 4 + p) * 2 + 1];
            float w  = awp[l * 4 + p];
            float lx = rx * W + ox - 0.5f;
            float ly = ry * H + oy - 0.5f;
            float x0f = floorf(lx), y0f = floorf(ly);
            int x0 = (int)x0f, y0 = (int)y0f;
            float wx1 = lx - x0f, wy1 = ly - y0f;
            float wx0 = 1.f - wx1, wy0 = 1.f - wy1;
            float s = 0.f;
#pragma unroll
            for (int dy = 0; dy < 2; dy++)
#pragma unroll
                for (int dx = 0; dx < 2; dx++) {
                    int xi = x0 + dx, yi = y0 + dy;
                    if (xi >= 0 && xi < W && yi >= 0 && yi < H) {
                        float cw = (dx ? wx1 : wx0) * (dy ? wy1 : wy0);
                        s += cw * bf2f(vbase[(size_t)(yi * W + xi) * 256]);
                    }
                }
            acc += w * s;
        }
    }
    out[(size_t)lm * 256 + h * 32 + ch] = f2bf(acc);
}

// out = LayerNorm(x + a) * g + b; writes fp32 out + bf16 mirror; in-place safe
__global__ void ln_res_kernel(const float* __restrict__ x, const float* __restrict__ a,
                              const float* __restrict__ g, const float* __restrict__ b,
                              float* __restrict__ out, ushortT* __restrict__ outh, int M)
{
    int wave = threadIdx.x >> 6;
    int lane = threadIdx.x & 63;
    int row = blockIdx.x * 4 + wave;
    if (row >= M) return;
    const float* xp = x + (size_t)row * 256;
    const float* ap = a + (size_t)row * 256;
    float v[4];
    float s = 0.f;
#pragma unroll
    for (int i = 0; i < 4; i++) { v[i] = xp[lane + i * 64] + ap[lane + i * 64]; s += v[i]; }
#pragma unroll
    for (int o = 32; o > 0; o >>= 1) s += __shfl_down(s, o);
    s = __shfl(s, 0);
    float mean = s * (1.f / 256.f);
    float vs = 0.f;
#pragma unroll
    for (int i = 0; i < 4; i++) { float d = v[i] - mean; vs += d * d; }
#pragma unroll
    for (int o = 32; o > 0; o >>= 1) vs += __shfl_down(vs, o);
    vs = __shfl(vs, 0);
    float inv = rsqrtf(vs * (1.f / 256.f) + 1e-5f);
    float* op = out + (size_t)row * 256;
    ushortT* oh = outh + (size_t)row * 256;
#pragma unroll
    for (int i = 0; i < 4; i++) {
        int d = lane + i * 64;
        float val = (v[i] - mean) * inv * g[d] + b[d];
        op[d] = val;
        oh[d] = f2bf(val);
    }
}

// Decoder self-attn over L=8 (batch). qkv fp32 chunk rows n_local*8+l; out bf16.
__global__ void mha_kernel(const float* __restrict__ qkv, ushortT* __restrict__ o, int nCnt)
{
    int t = blockIdx.x * blockDim.x + threadIdx.x;
    if (t >= nCnt * 64) return;
    int l = t & 7;
    int h = (t >> 3) & 7;
    int n = t >> 6;
    const float* qp = qkv + (size_t)(n * 8 + l) * 768 + h * 32;
    float q[32];
#pragma unroll
    for (int d = 0; d < 32; d++) q[d] = qp[d];
    float sc[8];
#pragma unroll
    for (int s = 0; s < 8; s++) {
        const float* kp = qkv + (size_t)(n * 8 + s) * 768 + 256 + h * 32;
        float acc = 0.f;
#pragma unroll
        for (int d = 0; d < 32; d++) acc = fmaf(q[d], kp[d], acc);
        sc[s] = acc * 0.17677669529663688f;
    }
    float mx = sc[0];
#pragma unroll
    for (int s = 1; s < 8; s++) mx = fmaxf(mx, sc[s]);
    float sum = 0.f;
#pragma unroll
    for (int s = 0; s < 8; s++) { sc[s] = expf(sc[s] - mx); sum += sc[s]; }
    float inv = 1.f / sum;
    float outv[32] = {};
#pragma unroll
    for (int s = 0; s < 8; s++) {
        const float* vp = qkv + (size_t)(n * 8 + s) * 768 + 512 + h * 32;
        float a = sc[s] * inv;
#pragma unroll
        for (int d = 0; d < 32; d++) outv[d] = fmaf(a, vp[d], outv[d]);
    }
    ushortT* op = o + (size_t)(n * 8 + l) * 256 + h * 32;
#pragma unroll
    for (int d = 0; d < 32; d++) op[d] = f2bf(outv[d]);
}

__global__ void copy_kernel(const float* __restrict__ src, float* __restrict__ dst, int n)
{
    int t = blockIdx.x * blockDim.x + threadIdx.x;
    if (t < n) dst[t] = src[t];
}

// ---------------------------------------------------------------------------
extern "C" void kernel_launch(void* const* d_in, const int* in_sizes, int n_in,
                              void* d_out, int out_size, void* d_ws, size_t ws_size,
                              hipStream_t stream)
{
    const float* feat0       = (const float*)d_in[0];
    const float* feat1       = (const float*)d_in[1];
    const float* feat2       = (const float*)d_in[2];
    const float* context     = (const float*)d_in[3];
    const float* query_embed = (const float*)d_in[4];
    const float* level_embed = (const float*)d_in[5];
    const float* enc_off_W = (const float*)d_in[6];
    const float* enc_off_b = (const float*)d_in[7];
    const float* enc_aw_W  = (const float*)d_in[8];
    const float* enc_aw_b  = (const float*)d_in[9];
    const float* enc_vp_W  = (const float*)d_in[10];
    const float* enc_vp_b  = (const float*)d_in[11];
    const float* enc_op_W  = (const float*)d_in[12];
    const float* enc_op_b  = (const float*)d_in[13];
    const float* enc_fc1_W = (const float*)d_in[14];
    const float* enc_fc1_b = (const float*)d_in[15];
    const float* enc_fc2_W = (const float*)d_in[16];
    const float* enc_fc2_b = (const float*)d_in[17];
    const float* enc_ln1_g = (const float*)d_in[18];
    const float* enc_ln1_b = (const float*)d_in[19];
    const float* enc_ln2_g = (const float*)d_in[20];
    const float* enc_ln2_b = (const float*)d_in[21];
    const float* dec_off_W = (const float*)d_in[22];
    const float* dec_off_b = (const float*)d_in[23];
    const float* dec_aw_W  = (const float*)d_in[24];
    const float* dec_aw_b  = (const float*)d_in[25];
    const float* dec_vp_W  = (const float*)d_in[26];
    const float* dec_vp_b  = (const float*)d_in[27];
    const float* dec_op_W  = (const float*)d_in[28];
    const float* dec_op_b  = (const float*)d_in[29];
    const float* dec_fc1_W = (const float*)d_in[30];
    const float* dec_fc1_b = (const float*)d_in[31];
    const float* dec_fc2_W = (const float*)d_in[32];
    const float* dec_fc2_b = (const float*)d_in[33];
    const float* dec_ln1_g = (const float*)d_in[34];
    const float* dec_ln1_b = (const float*)d_in[35];
    const float* dec_ln2_g = (const float*)d_in[36];
    const float* dec_ln2_b = (const float*)d_in[37];
    const float* sa_in_W   = (const float*)d_in[38];
    const float* sa_in_b   = (const float*)d_in[39];
    const float* sa_out_W  = (const float*)d_in[40];
    const float* sa_out_b  = (const float*)d_in[41];
    const float* dec_ln3_g = (const float*)d_in[42];
    const float* dec_ln3_b = (const float*)d_in[43];

    const int ME = BSZ * S_TOT;       // 37800
    const int MD = BSZ * NQRY;        // 28800
    const int EW = ME * D_MODEL;      // 9,676,800
    const int DW = MD * D_MODEL;      // 7,372,800

    // ---- workspace layout (byte-based, 256B aligned) ----
    char* base = (char*)d_ws;
    size_t off = 0;
    auto alloc = [&](size_t bytes) -> char* {
        char* p = base + off;
        off += (bytes + 255) & ~(size_t)255;
        return p;
    };
    float*   Xb    = (float*)alloc((size_t)EW * 4);
    float*   TGTb  = (float*)alloc((size_t)DW * 4);
    float*   POSb  = (float*)alloc((size_t)S_TOT * 256 * 4);
    float*   REFEb = (float*)alloc((size_t)S_TOT * 2 * 4);
    float*   REFDb = (float*)alloc((size_t)NQRY * 2 * 4);
    ushortT* Xh    = (ushortT*)alloc((size_t)EW * 2);
    ushortT* Vh    = (ushortT*)alloc((size_t)EW * 2);
    ushortT* TGTh  = (ushortT*)alloc((size_t)DW * 2);
    ushortT* Wbf   = (ushortT*)alloc((size_t)5160960 * 2);
    char*    UNION = alloc((size_t)34406400);
    float*   Yf    = (float*)alloc((size_t)CH * 256 * 4);
    if (ws_size < off) return;   // refuse to fault

    // UNION sub-views (phase-disjoint):
    float*   QKVf = (float*)UNION;                          // [CH,768] f32
    ushortT* SOh  = (ushortT*)(UNION + 29491200);           // [CH,256] bf16
    float*   OFFf = (float*)UNION;                          // [CH,192] f32
    float*   AWf  = (float*)(UNION + 7372800);              // [CH,96]  f32
    ushortT* Qh   = (ushortT*)(UNION + 11059200);           // [CH,256] bf16
    ushortT* OUTh = (ushortT*)(UNION + 15974400);           // [CH,256] bf16
    ushortT* HIDh = (ushortT*)UNION;                        // [CH,1024] bf16

    // bf16 weight mirrors
    size_t wo = 0;
    auto walloc = [&](size_t elems) -> ushortT* { ushortT* p = Wbf + wo; wo += elems; return p; };
    ushortT* h_enc_off = walloc(3 * 49152);
    ushortT* h_enc_aw  = walloc(3 * 24576);
    ushortT* h_enc_vp  = walloc(3 * 65536);
    ushortT* h_enc_op  = walloc(3 * 65536);
    ushortT* h_enc_fc1 = walloc(3 * 262144);
    ushortT* h_enc_fc2 = walloc(3 * 262144);
    ushortT* h_dec_off = walloc(3 * 49152);
    ushortT* h_dec_aw  = walloc(3 * 24576);
    ushortT* h_dec_vp  = walloc(3 * 65536);
    ushortT* h_dec_op  = walloc(3 * 65536);
    ushortT* h_dec_fc1 = walloc(3 * 262144);
    ushortT* h_dec_fc2 = walloc(3 * 262144);
    ushortT* h_sa_in   = walloc(3 * 196608);
    ushortT* h_sa_out  = walloc(3 * 65536);

    auto conv = [&](const float* s, ushortT* d, int n) {
        hipLaunchKernelGGL(f2bf_kernel, dim3((n + 255) / 256), dim3(256), 0, stream, s, d, n);
    };
    conv(enc_off_W, h_enc_off, 3 * 49152);
    conv(enc_aw_W,  h_enc_aw,  3 * 24576);
    conv(enc_vp_W,  h_enc_vp,  3 * 65536);
    conv(enc_op_W,  h_enc_op,  3 * 65536);
    conv(enc_fc1_W, h_enc_fc1, 3 * 262144);
    conv(enc_fc2_W, h_enc_fc2, 3 * 262144);
    conv(dec_off_W, h_dec_off, 3 * 49152);
    conv(dec_aw_W,  h_dec_aw,  3 * 24576);
    conv(dec_vp_W,  h_dec_vp,  3 * 65536);
    conv(dec_op_W,  h_dec_op,  3 * 65536);
    conv(dec_fc1_W, h_dec_fc1, 3 * 262144);
    conv(dec_fc2_W, h_dec_fc2, 3 * 262144);
    conv(sa_in_W,   h_sa_in,   3 * 196608);
    conv(sa_out_W,  h_sa_out,  3 * 65536);

    // ---- setup ----
    hipLaunchKernelGGL(build_pos_kernel, dim3((S_TOT * 256 + 255) / 256), dim3(256), 0, stream,
                       level_embed, POSb);
    hipLaunchKernelGGL(build_ref_kernel, dim3((S_TOT + NQRY + 255) / 256), dim3(256), 0, stream,
                       REFEb, REFDb);
    hipLaunchKernelGGL(build_src_kernel, dim3((EW + 255) / 256), dim3(256), 0, stream,
                       feat0, feat1, feat2, Xb, Xh);
    hipLaunchKernelGGL(build_tgt_kernel, dim3((DW + 255) / 256), dim3(256), 0, stream,
                       context, query_embed, TGTb, TGTh);

    // ---- encoder ----
    for (int i = 0; i < 3; i++) {
        gemm_bf16(Xh, h_enc_vp + (size_t)i * 65536, enc_vp_b + i * 256, Vh, ME, 256, 256, 0, 1, stream);
        for (int r0 = 0; r0 < ME; r0 += CH) {
            int rows = (ME - r0 < CH) ? (ME - r0) : CH;
            hipLaunchKernelGGL(add_pos_chunk_kernel, dim3((rows * 256 + 255) / 256), dim3(256),
                               0, stream, Xb, POSb, Qh, r0, rows);
            gemm_bf16(Qh, h_enc_off + (size_t)i * 49152, enc_off_b + i * 192, OFFf, rows, 192, 256, 0, 0, stream);
            gemm_bf16(Qh, h_enc_aw + (size_t)i * 24576, enc_aw_b + i * 96, AWf, rows, 96, 256, 0, 0, stream);
            hipLaunchKernelGGL(aw_softmax_kernel, dim3((rows * 8 + 255) / 256), dim3(256), 0, stream,
                               AWf, rows * 8);
            hipLaunchKernelGGL(msda_kernel, dim3(rows), dim3(256), 0, stream,
                               Vh, OFFf, AWf, REFEb, OUTh, 0, r0);
            gemm_bf16(OUTh, h_enc_op + (size_t)i * 65536, enc_op_b + i * 256, Yf, rows, 256, 256, 0, 0, stream);
            hipLaunchKernelGGL(ln_res_kernel, dim3((rows + 3) / 4), dim3(256), 0, stream,
                               Xb + (size_t)r0 * 256, Yf, enc_ln1_g + i * 256, enc_ln1_b + i * 256,
                               Xb + (size_t)r0 * 256, Xh + (size_t)r0 * 256, rows);
            gemm_bf16(Xh + (size_t)r0 * 256, h_enc_fc1 + (size_t)i * 262144, enc_fc1_b + i * 1024,
                      HIDh, rows, 1024, 256, 1, 1, stream);
            gemm_bf16(HIDh, h_enc_fc2 + (size_t)i * 262144, enc_fc2_b + i * 256, Yf, rows, 256, 1024, 0, 0, stream);
            hipLaunchKernelGGL(ln_res_kernel, dim3((rows + 3) / 4), dim3(256), 0, stream,
                               Xb + (size_t)r0 * 256, Yf, enc_ln2_g + i * 256, enc_ln2_b + i * 256,
                               Xb + (size_t)r0 * 256, Xh + (size_t)r0 * 256, rows);
        }
    }
    // Xb/Xh now hold `memory`.

    // ---- decoder (state kept in [NQ,BS,D] row order throughout) ----
    for (int i = 0; i < 3; i++) {
        for (int c = 0; c < 3; c++) {
            size_t r0 = (size_t)c * CH;
            gemm_bf16(TGTh + r0 * 256, h_sa_in + (size_t)i * 196608, sa_in_b + i * 768,
                      QKVf, CH, 768, 256, 0, 0, stream);
            hipLaunchKernelGGL(mha_kernel, dim3((1200 * 64 + 255) / 256), dim3(256), 0, stream,
                               QKVf, SOh, 1200);
            gemm_bf16(SOh, h_sa_out + (size_t)i * 65536, sa_out_b + i * 256, Yf, CH, 256, 256, 0, 0, stream);
            hipLaunchKernelGGL(ln_res_kernel, dim3((CH + 3) / 4), dim3(256), 0, stream,
                               TGTb + r0 * 256, Yf, dec_ln2_g + i * 256, dec_ln2_b + i * 256,
                               TGTb + r0 * 256, TGTh + r0 * 256, CH);
        }
        gemm_bf16(Xh, h_dec_vp + (size_t)i * 65536, dec_vp_b + i * 256, Vh, ME, 256, 256, 0, 1, stream);
        for (int c = 0; c < 3; c++) {
            size_t r0 = (size_t)c * CH;
            gemm_bf16(TGTh + r0 * 256, h_dec_off + (size_t)i * 49152, dec_off_b + i * 192,
                      OFFf, CH, 192, 256, 0, 0, stream);
            gemm_bf16(TGTh + r0 * 256, h_dec_aw + (size_t)i * 24576, dec_aw_b + i * 96,
                      AWf, CH, 96, 256, 0, 0, stream);
            hipLaunchKernelGGL(aw_softmax_kernel, dim3((CH * 8 + 255) / 256), dim3(256), 0, stream,
                               AWf, CH * 8);
            hipLaunchKernelGGL(msda_kernel, dim3(CH), dim3(256), 0, stream,
                               Vh, OFFf, AWf, REFDb, OUTh, 1, (int)r0);
            gemm_bf16(OUTh, h_dec_op + (size_t)i * 65536, dec_op_b + i * 256, Yf, CH, 256, 256, 0, 0, stream);
            hipLaunchKernelGGL(ln_res_kernel, dim3((CH + 3) / 4), dim3(256), 0, stream,
                               TGTb + r0 * 256, Yf, dec_ln1_g + i * 256, dec_ln1_b + i * 256,
                               TGTb + r0 * 256, TGTh + r0 * 256, CH);
            gemm_bf16(TGTh + r0 * 256, h_dec_fc1 + (size_t)i * 262144, dec_fc1_b + i * 1024,
                      HIDh, CH, 1024, 256, 1, 1, stream);
            gemm_bf16(HIDh, h_dec_fc2 + (size_t)i * 262144, dec_fc2_b + i * 256, Yf, CH, 256, 1024, 0, 0, stream);
            hipLaunchKernelGGL(ln_res_kernel, dim3((CH + 3) / 4), dim3(256), 0, stream,
                               TGTb + r0 * 256, Yf, dec_ln3_g + i * 256, dec_ln3_b + i * 256,
                               TGTb + r0 * 256, TGTh + r0 * 256, CH);
        }
    }

    hipLaunchKernelGGL(copy_kernel, dim3((DW + 255) / 256), dim3(256), 0, stream,
                       TGTb, (float*)d_out, DW);
}

// Round 4
// 3849.641 us; speedup vs baseline: 3.7716x; 1.2866x over previous
//
#include <hip/hip_runtime.h>
#include <cmath>

#define D_MODEL 256
#define NHEADS 8
#define BSZ 8
#define S_TOT 4725
#define NQRY 3600
#define CH 19200   // chunk rows

typedef unsigned short ushortT;
using bf16x8  = __attribute__((ext_vector_type(8))) __bf16;
using floatx4 = __attribute__((ext_vector_type(4))) float;

__device__ __forceinline__ ushortT f2bf(float f)
{
    union { float f; unsigned u; } v; v.f = f;
    unsigned r = v.u + 0x7FFFu + ((v.u >> 16) & 1u);
    return (ushortT)(r >> 16);
}
__device__ __forceinline__ float bf2f(ushortT u)
{
    union { unsigned u; float f; } v; v.u = ((unsigned)u) << 16;
    return v.f;
}

#define GLD16(gp, lp) __builtin_amdgcn_global_load_lds( \
    (const __attribute__((address_space(1))) void*)(gp), \
    (__attribute__((address_space(3))) void*)(lp), 16, 0, 0)

// ---------------------------------------------------------------------------
// bf16 MFMA GEMM with async global->LDS staging.
// C[M,N] = act(A[M,K] @ W[N,K]^T + bias[N]); K % 32 == 0. Tile 128x128, BK=32.
// LDS layout [128][32] bf16 unpadded (64B rows) — required by global_load_lds
// wave-uniform-base + lane*16 dest rule (m97 recipe).
// ---------------------------------------------------------------------------
template<int RELU, int OUTBF>
__global__ __launch_bounds__(256) void gemm_bf16_kernel(
    const ushortT* __restrict__ A, const ushortT* __restrict__ W,
    const float* __restrict__ bias, void* __restrict__ Cout,
    int M, int N, int K)
{
    __shared__ ushortT As[128 * 32];
    __shared__ ushortT Bs[128 * 32];
    const int tid  = threadIdx.x;
    const int lane = tid & 63;
    const int wid  = tid >> 6;
    const int bm = blockIdx.x * 128;
    const int bn = blockIdx.y * 128;
    const int wm = (wid & 1) * 64;
    const int wn = (wid >> 1) * 64;
    const int col16 = lane & 15;
    const int quad  = lane >> 4;
    const int srow = lane >> 2;    // staging: row-within-16-group
    const int scg  = lane & 3;     // staging: 16B chunk within 64B row

    floatx4 acc[4][4];
#pragma unroll
    for (int i = 0; i < 4; i++)
#pragma unroll
        for (int j = 0; j < 4; j++) acc[i][j] = (floatx4){0.f, 0.f, 0.f, 0.f};

    const int rbase = wid * 32;    // this wave stages tile rows [rbase, rbase+32)
    for (int k0 = 0; k0 < K; k0 += 32) {
        if (k0) __syncthreads();
#pragma unroll
        for (int j = 0; j < 2; j++) {
            int row = rbase + j * 16 + srow;
            int gm = bm + row; if (gm >= M) gm = M - 1;
            GLD16(A + (size_t)gm * K + k0 + scg * 8, &As[(rbase + j * 16) * 32]);
            int gn = bn + row; if (gn >= N) gn = N - 1;
            GLD16(W + (size_t)gn * K + k0 + scg * 8, &Bs[(rbase + j * 16) * 32]);
        }
        __syncthreads();
        bf16x8 av[4], bv[4];
#pragma unroll
        for (int i = 0; i < 4; i++) {
            av[i] = *(const bf16x8*)&As[(wm + i * 16 + col16) * 32 + quad * 8];
            bv[i] = *(const bf16x8*)&Bs[(wn + i * 16 + col16) * 32 + quad * 8];
        }
#pragma unroll
        for (int mi = 0; mi < 4; mi++)
#pragma unroll
            for (int ni = 0; ni < 4; ni++)
                acc[mi][ni] = __builtin_amdgcn_mfma_f32_16x16x32_bf16(
                    av[mi], bv[ni], acc[mi][ni], 0, 0, 0);
    }

    // Epilogue: D row = quad*4+r, col = lane&15
#pragma unroll
    for (int ni = 0; ni < 4; ni++) {
        int gn = bn + wn + ni * 16 + col16;
        if (gn >= N) continue;
        float bs = bias[gn];
#pragma unroll
        for (int mi = 0; mi < 4; mi++) {
#pragma unroll
            for (int r = 0; r < 4; r++) {
                int gm = bm + wm + mi * 16 + quad * 4 + r;
                if (gm >= M) continue;
                float v = acc[mi][ni][r] + bs;
                if (RELU) v = fmaxf(v, 0.f);
                if (OUTBF) ((ushortT*)Cout)[(size_t)gm * N + gn] = f2bf(v);
                else       ((float*)Cout)[(size_t)gm * N + gn] = v;
            }
        }
    }
}

static inline void gemm_bf16(const ushortT* A, const ushortT* W, const float* bias,
                             void* C, int M, int N, int K, int relu, int outbf,
                             hipStream_t s)
{
    dim3 g((M + 127) / 128, (N + 127) / 128);
    if (relu) {
        if (outbf) hipLaunchKernelGGL((gemm_bf16_kernel<1,1>), g, dim3(256), 0, s, A, W, bias, C, M, N, K);
        else       hipLaunchKernelGGL((gemm_bf16_kernel<1,0>), g, dim3(256), 0, s, A, W, bias, C, M, N, K);
    } else {
        if (outbf) hipLaunchKernelGGL((gemm_bf16_kernel<0,1>), g, dim3(256), 0, s, A, W, bias, C, M, N, K);
        else       hipLaunchKernelGGL((gemm_bf16_kernel<0,0>), g, dim3(256), 0, s, A, W, bias, C, M, N, K);
    }
}

// ---------------------------------------------------------------------------
__global__ void f2bf_kernel(const float* __restrict__ src, ushortT* __restrict__ dst, int n)
{
    int t = blockIdx.x * blockDim.x + threadIdx.x;
    if (t < n) dst[t] = f2bf(src[t]);
}

// combined [3][288][256] weight: rows 0-191 off, 192-287 aw
__global__ void conv_offaw_kernel(const float* __restrict__ offW, const float* __restrict__ awW,
                                  ushortT* __restrict__ dst)
{
    int t = blockIdx.x * blockDim.x + threadIdx.x;
    if (t >= 3 * 288 * 256) return;
    int c = t & 255;
    int r = (t >> 8) % 288;
    int i = t / (288 * 256);
    float v = (r < 192) ? offW[((size_t)i * 192 + r) * 256 + c]
                        : awW[((size_t)i * 96 + (r - 192)) * 256 + c];
    dst[t] = f2bf(v);
}

__global__ void conv_offaw_bias_kernel(const float* __restrict__ offb, const float* __restrict__ awb,
                                       float* __restrict__ dst)
{
    int t = blockIdx.x * blockDim.x + threadIdx.x;
    if (t >= 3 * 288) return;
    int r = t % 288;
    int i = t / 288;
    dst[t] = (r < 192) ? offb[i * 192 + r] : awb[i * 96 + (r - 192)];
}

__device__ __forceinline__ void level_of(int s, int& l, int& H, int& W, int& hw)
{
    if (s < 3600)      { l = 0; H = 60; W = 60; hw = s; }
    else if (s < 4500) { l = 1; H = 30; W = 30; hw = s - 3600; }
    else               { l = 2; H = 15; W = 15; hw = s - 4500; }
}

__global__ void build_src_kernel(const float* __restrict__ f0, const float* __restrict__ f1,
                                 const float* __restrict__ f2, float* __restrict__ X,
                                 ushortT* __restrict__ Xh)
{
    int t = blockIdx.x * blockDim.x + threadIdx.x;
    if (t >= BSZ * S_TOT * D_MODEL) return;
    int d = t & 255;
    int r = t >> 8;
    int s = r % S_TOT;
    int b = r / S_TOT;
    int l, H, W, hw; level_of(s, l, H, W, hw);
    const float* f = (l == 0) ? f0 : (l == 1) ? f1 : f2;
    float v = f[((size_t)b * D_MODEL + d) * (size_t)(H * W) + hw];
    X[t] = v;
    Xh[t] = f2bf(v);
}

__global__ void build_pos_kernel(const float* __restrict__ level_embed, float* __restrict__ pos)
{
    int t = blockIdx.x * blockDim.x + threadIdx.x;
    if (t >= S_TOT * D_MODEL) return;
    int d = t & 255;
    int s = t >> 8;
    int l, H, W, hw; level_of(s, l, H, W, hw);
    int y = hw / W, x = hw % W;
    int dd = (d < 128) ? d : d - 128;
    float v = (d < 128)
        ? ((float)(y + 1)) / ((float)H + 1e-6f) * 6.28318530717958647692f
        : ((float)(x + 1)) / ((float)W + 1e-6f) * 6.28318530717958647692f;
    float tpow = powf(10000.f, (float)(2 * (dd >> 1)) * (1.f / 128.f));
    float arg = v / tpow;
    float val = (dd & 1) ? cosf(arg) : sinf(arg);
    pos[t] = val + level_embed[l * D_MODEL + d];
}

__global__ void build_ref_kernel(float* __restrict__ refE, float* __restrict__ refD)
{
    int t = blockIdx.x * blockDim.x + threadIdx.x;
    if (t < S_TOT) {
        int l, H, W, hw; level_of(t, l, H, W, hw);
        int y = hw / W, x = hw % W;
        refE[2 * t]     = ((float)x + 0.5f) / (float)W;
        refE[2 * t + 1] = ((float)y + 0.5f) / (float)H;
    } else if (t < S_TOT + NQRY) {
        int q = t - S_TOT;
        int y = q / 60, x = q % 60;
        refD[2 * q]     = ((float)x + 0.5f) / 60.f;
        refD[2 * q + 1] = ((float)y + 0.5f) / 60.f;
    }
}

__global__ void build_tgt_kernel(const float* __restrict__ context, const float* __restrict__ qe,
                                 float* __restrict__ TGT, ushortT* __restrict__ TGTh)
{
    int t = blockIdx.x * blockDim.x + threadIdx.x;
    if (t >= NQRY * BSZ * D_MODEL) return;
    int d = t & 255;
    int nq = t >> 11;
    float v = context[t] + qe[nq * D_MODEL + d];
    TGT[t] = v;
    TGTh[t] = f2bf(v);
}

__global__ void add_pos_chunk_kernel(const float* __restrict__ X, const float* __restrict__ pos,
                                     ushortT* __restrict__ Qh, int r0, int rows)
{
    int t = blockIdx.x * blockDim.x + threadIdx.x;
    if (t >= rows * D_MODEL) return;
    int d = t & 255;
    int m = r0 + (t >> 8);
    int s = m % S_TOT;
    Qh[t] = f2bf(X[(size_t)m * D_MODEL + d] + pos[(size_t)s * D_MODEL + d]);
}

// MSDA sampling + inline per-head softmax over 12 logits.
// value bf16 [BSZ,S_TOT,256]; oa f32 chunk [rows,288] (off 0-191, aw-logits 192-287).
// mode 0 (enc): b=m/S_TOT, q=m%S_TOT.  mode 1 (dec, [NQ,BS] order): q=m>>3, b=m&7.
__global__ void msda_kernel(const ushortT* __restrict__ value, const float* __restrict__ oa,
                            const float* __restrict__ ref, ushortT* __restrict__ out,
                            int mode, int m0)
{
    int lm = blockIdx.x;
    int m = m0 + lm;
    int h = threadIdx.x >> 5;
    int ch = threadIdx.x & 31;
    int b, q;
    if (mode == 0) { b = m / S_TOT; q = m - b * S_TOT; }
    else           { q = m >> 3;    b = m & 7; }
    float rx = ref[2 * q], ry = ref[2 * q + 1];
    const float* offp = oa + (size_t)lm * 288 + h * 24;
    const float* awp  = oa + (size_t)lm * 288 + 192 + h * 12;
    float wgt[12];
    {
        float mx = awp[0];
#pragma unroll
        for (int i = 1; i < 12; i++) mx = fmaxf(mx, awp[i]);
        float ssum = 0.f;
#pragma unroll
        for (int i = 0; i < 12; i++) { wgt[i] = expf(awp[i] - mx); ssum += wgt[i]; }
        float inv = 1.f / ssum;
#pragma unroll
        for (int i = 0; i < 12; i++) wgt[i] *= inv;
    }
    float acc = 0.f;
    const int HWs[3][3] = {{60, 60, 0}, {30, 30, 3600}, {15, 15, 4500}};
#pragma unroll
    for (int l = 0; l < 3; l++) {
        int H = HWs[l][0], W = HWs[l][1], s0 = HWs[l][2];
        const ushortT* vbase = value + ((size_t)b * S_TOT + s0) * 256 + h * 32 + ch;
#pragma unroll
        for (int p = 0; p < 4; p++) {
            float ox = offp[(l * 4 + p) * 2];
            float oy = offp[(l * 4 + p) * 2 + 1];
            float w  = wgt[l * 4 + p];
            float lx = rx * W + ox - 0.5f;
            float ly = ry * H + oy - 0.5f;
            float x0f = floorf(lx), y0f = floorf(ly);
            int x0 = (int)x0f, y0 = (int)y0f;
            float wx1 = lx - x0f, wy1 = ly - y0f;
            float wx0 = 1.f - wx1, wy0 = 1.f - wy1;
            float s = 0.f;
#pragma unroll
            for (int dy = 0; dy < 2; dy++)
#pragma unroll
                for (int dx = 0; dx < 2; dx++) {
                    int xi = x0 + dx, yi = y0 + dy;
                    if (xi >= 0 && xi < W && yi >= 0 && yi < H) {
                        float cw = (dx ? wx1 : wx0) * (dy ? wy1 : wy0);
                        s += cw * bf2f(vbase[(size_t)(yi * W + xi) * 256]);
                    }
                }
            acc += w * s;
        }
    }
    out[(size_t)lm * 256 + h * 32 + ch] = f2bf(acc);
}

// out = LayerNorm(x + a) * g + b; a is bf16; writes fp32 out + bf16 mirror
__global__ void ln_res_kernel(const float* __restrict__ x, const ushortT* __restrict__ a,
                              const float* __restrict__ g, const float* __restrict__ b,
                              float* __restrict__ out, ushortT* __restrict__ outh, int M)
{
    int wave = threadIdx.x >> 6;
    int lane = threadIdx.x & 63;
    int row = blockIdx.x * 4 + wave;
    if (row >= M) return;
    const float* xp = x + (size_t)row * 256;
    const ushortT* ap = a + (size_t)row * 256;
    float v[4];
    float s = 0.f;
#pragma unroll
    for (int i = 0; i < 4; i++) { v[i] = xp[lane + i * 64] + bf2f(ap[lane + i * 64]); s += v[i]; }
#pragma unroll
    for (int o = 32; o > 0; o >>= 1) s += __shfl_down(s, o);
    s = __shfl(s, 0);
    float mean = s * (1.f / 256.f);
    float vs = 0.f;
#pragma unroll
    for (int i = 0; i < 4; i++) { float d = v[i] - mean; vs += d * d; }
#pragma unroll
    for (int o = 32; o > 0; o >>= 1) vs += __shfl_down(vs, o);
    vs = __shfl(vs, 0);
    float inv = rsqrtf(vs * (1.f / 256.f) + 1e-5f);
    float* op = out + (size_t)row * 256;
    ushortT* oh = outh + (size_t)row * 256;
#pragma unroll
    for (int i = 0; i < 4; i++) {
        int d = lane + i * 64;
        float val = (v[i] - mean) * inv * g[d] + b[d];
        op[d] = val;
        oh[d] = f2bf(val);
    }
}

// Decoder self-attn over L=8 (batch). qkv bf16 chunk rows n_local*8+l; out bf16.
__global__ void mha_kernel(const ushortT* __restrict__ qkv, ushortT* __restrict__ o, int nCnt)
{
    int t = blockIdx.x * blockDim.x + threadIdx.x;
    if (t >= nCnt * 64) return;
    int l = t & 7;
    int h = (t >> 3) & 7;
    int n = t >> 6;
    const ushortT* qp = qkv + (size_t)(n * 8 + l) * 768 + h * 32;
    float q[32];
#pragma unroll
    for (int d = 0; d < 32; d++) q[d] = bf2f(qp[d]);
    float sc[8];
#pragma unroll
    for (int s = 0; s < 8; s++) {
        const ushortT* kp = qkv + (size_t)(n * 8 + s) * 768 + 256 + h * 32;
        float acc = 0.f;
#pragma unroll
        for (int d = 0; d < 32; d++) acc = fmaf(q[d], bf2f(kp[d]), acc);
        sc[s] = acc * 0.17677669529663688f;
    }
    float mx = sc[0];
#pragma unroll
    for (int s = 1; s < 8; s++) mx = fmaxf(mx, sc[s]);
    float sum = 0.f;
#pragma unroll
    for (int s = 0; s < 8; s++) { sc[s] = expf(sc[s] - mx); sum += sc[s]; }
    float inv = 1.f / sum;
    float outv[32] = {};
#pragma unroll
    for (int s = 0; s < 8; s++) {
        const ushortT* vp = qkv + (size_t)(n * 8 + s) * 768 + 512 + h * 32;
        float a = sc[s] * inv;
#pragma unroll
        for (int d = 0; d < 32; d++) outv[d] = fmaf(a, bf2f(vp[d]), outv[d]);
    }
    ushortT* op = o + (size_t)(n * 8 + l) * 256 + h * 32;
#pragma unroll
    for (int d = 0; d < 32; d++) op[d] = f2bf(outv[d]);
}

// ---------------------------------------------------------------------------
extern "C" void kernel_launch(void* const* d_in, const int* in_sizes, int n_in,
                              void* d_out, int out_size, void* d_ws, size_t ws_size,
                              hipStream_t stream)
{
    const float* feat0       = (const float*)d_in[0];
    const float* feat1       = (const float*)d_in[1];
    const float* feat2       = (const float*)d_in[2];
    const float* context     = (const float*)d_in[3];
    const float* query_embed = (const float*)d_in[4];
    const float* level_embed = (const float*)d_in[5];
    const float* enc_off_W = (const float*)d_in[6];
    const float* enc_off_b = (const float*)d_in[7];
    const float* enc_aw_W  = (const float*)d_in[8];
    const float* enc_aw_b  = (const float*)d_in[9];
    const float* enc_vp_W  = (const float*)d_in[10];
    const float* enc_vp_b  = (const float*)d_in[11];
    const float* enc_op_W  = (const float*)d_in[12];
    const float* enc_op_b  = (const float*)d_in[13];
    const float* enc_fc1_W = (const float*)d_in[14];
    const float* enc_fc1_b = (const float*)d_in[15];
    const float* enc_fc2_W = (const float*)d_in[16];
    const float* enc_fc2_b = (const float*)d_in[17];
    const float* enc_ln1_g = (const float*)d_in[18];
    const float* enc_ln1_b = (const float*)d_in[19];
    const float* enc_ln2_g = (const float*)d_in[20];
    const float* enc_ln2_b = (const float*)d_in[21];
    const float* dec_off_W = (const float*)d_in[22];
    const float* dec_off_b = (const float*)d_in[23];
    const float* dec_aw_W  = (const float*)d_in[24];
    const float* dec_aw_b  = (const float*)d_in[25];
    const float* dec_vp_W  = (const float*)d_in[26];
    const float* dec_vp_b  = (const float*)d_in[27];
    const float* dec_op_W  = (const float*)d_in[28];
    const float* dec_op_b  = (const float*)d_in[29];
    const float* dec_fc1_W = (const float*)d_in[30];
    const float* dec_fc1_b = (const float*)d_in[31];
    const float* dec_fc2_W = (const float*)d_in[32];
    const float* dec_fc2_b = (const float*)d_in[33];
    const float* dec_ln1_g = (const float*)d_in[34];
    const float* dec_ln1_b = (const float*)d_in[35];
    const float* dec_ln2_g = (const float*)d_in[36];
    const float* dec_ln2_b = (const float*)d_in[37];
    const float* sa_in_W   = (const float*)d_in[38];
    const float* sa_in_b   = (const float*)d_in[39];
    const float* sa_out_W  = (const float*)d_in[40];
    const float* sa_out_b  = (const float*)d_in[41];
    const float* dec_ln3_g = (const float*)d_in[42];
    const float* dec_ln3_b = (const float*)d_in[43];

    const int ME = BSZ * S_TOT;       // 37800
    const int MD = BSZ * NQRY;        // 28800
    const int EW = ME * D_MODEL;      // 9,676,800
    const int DW = MD * D_MODEL;      // 7,372,800

    // ---- workspace layout (byte-based, 256B aligned); total ~188.5 MB ----
    char* base = (char*)d_ws;
    size_t off = 0;
    auto alloc = [&](size_t bytes) -> char* {
        char* p = base + off;
        off += (bytes + 255) & ~(size_t)255;
        return p;
    };
    float*   Xb    = (float*)alloc((size_t)EW * 4);
    float*   TGTb  = (float*)alloc((size_t)DW * 4);
    float*   POSb  = (float*)alloc((size_t)S_TOT * 256 * 4);
    float*   REFEb = (float*)alloc((size_t)S_TOT * 2 * 4);
    float*   REFDb = (float*)alloc((size_t)NQRY * 2 * 4);
    ushortT* Xh    = (ushortT*)alloc((size_t)EW * 2);
    ushortT* Vh    = (ushortT*)alloc((size_t)EW * 2);
    ushortT* TGTh  = (ushortT*)alloc((size_t)DW * 2);
    ushortT* Wbf   = (ushortT*)alloc((size_t)5160960 * 2);
    float*   OBIAS = (float*)alloc((size_t)2 * 3 * 288 * 4);
    char*    R     = alloc((size_t)41779200);        // time-multiplexed scratch
    ushortT* Yh    = (ushortT*)alloc((size_t)CH * 256 * 2);
    if (ws_size < off) return;   // refuse to fault

    // R sub-views (phase-disjoint):
    ushortT* Qh   = (ushortT*)R;                      // [CH,256] bf16
    float*   OAf  = (float*)(R + 9830400);            // [CH,288] f32
    ushortT* OUTh = (ushortT*)(R + 31948800);         // [CH,256] bf16
    ushortT* QKVh = (ushortT*)R;                      // [CH,768] bf16
    ushortT* SOh  = (ushortT*)(R + 29491200);         // [CH,256] bf16
    ushortT* HIDh = (ushortT*)R;                      // [CH,1024] bf16

    // bf16 weight mirrors
    size_t wo = 0;
    auto walloc = [&](size_t elems) -> ushortT* { ushortT* p = Wbf + wo; wo += elems; return p; };
    ushortT* h_enc_offaw = walloc(3 * 288 * 256);
    ushortT* h_enc_vp    = walloc(3 * 65536);
    ushortT* h_enc_op    = walloc(3 * 65536);
    ushortT* h_enc_fc1   = walloc(3 * 262144);
    ushortT* h_enc_fc2   = walloc(3 * 262144);
    ushortT* h_dec_offaw = walloc(3 * 288 * 256);
    ushortT* h_dec_vp    = walloc(3 * 65536);
    ushortT* h_dec_op    = walloc(3 * 65536);
    ushortT* h_dec_fc1   = walloc(3 * 262144);
    ushortT* h_dec_fc2   = walloc(3 * 262144);
    ushortT* h_sa_in     = walloc(3 * 196608);
    ushortT* h_sa_out    = walloc(3 * 65536);
    float* enc_oab = OBIAS;            // [3][288]
    float* dec_oab = OBIAS + 3 * 288;  // [3][288]

    auto conv = [&](const float* s, ushortT* d, int n) {
        hipLaunchKernelGGL(f2bf_kernel, dim3((n + 255) / 256), dim3(256), 0, stream, s, d, n);
    };
    hipLaunchKernelGGL(conv_offaw_kernel, dim3((3 * 288 * 256 + 255) / 256), dim3(256), 0, stream,
                       enc_off_W, enc_aw_W, h_enc_offaw);
    hipLaunchKernelGGL(conv_offaw_kernel, dim3((3 * 288 * 256 + 255) / 256), dim3(256), 0, stream,
                       dec_off_W, dec_aw_W, h_dec_offaw);
    hipLaunchKernelGGL(conv_offaw_bias_kernel, dim3(4), dim3(256), 0, stream,
                       enc_off_b, enc_aw_b, enc_oab);
    hipLaunchKernelGGL(conv_offaw_bias_kernel, dim3(4), dim3(256), 0, stream,
                       dec_off_b, dec_aw_b, dec_oab);
    conv(enc_vp_W,  h_enc_vp,  3 * 65536);
    conv(enc_op_W,  h_enc_op,  3 * 65536);
    conv(enc_fc1_W, h_enc_fc1, 3 * 262144);
    conv(enc_fc2_W, h_enc_fc2, 3 * 262144);
    conv(dec_vp_W,  h_dec_vp,  3 * 65536);
    conv(dec_op_W,  h_dec_op,  3 * 65536);
    conv(dec_fc1_W, h_dec_fc1, 3 * 262144);
    conv(dec_fc2_W, h_dec_fc2, 3 * 262144);
    conv(sa_in_W,   h_sa_in,   3 * 196608);
    conv(sa_out_W,  h_sa_out,  3 * 65536);

    // ---- setup ----
    hipLaunchKernelGGL(build_pos_kernel, dim3((S_TOT * 256 + 255) / 256), dim3(256), 0, stream,
                       level_embed, POSb);
    hipLaunchKernelGGL(build_ref_kernel, dim3((S_TOT + NQRY + 255) / 256), dim3(256), 0, stream,
                       REFEb, REFDb);
    hipLaunchKernelGGL(build_src_kernel, dim3((EW + 255) / 256), dim3(256), 0, stream,
                       feat0, feat1, feat2, Xb, Xh);
    hipLaunchKernelGGL(build_tgt_kernel, dim3((DW + 255) / 256), dim3(256), 0, stream,
                       context, query_embed, TGTb, TGTh);

    // ---- encoder ----
    for (int i = 0; i < 3; i++) {
        gemm_bf16(Xh, h_enc_vp + (size_t)i * 65536, enc_vp_b + i * 256, Vh, ME, 256, 256, 0, 1, stream);
        for (int r0 = 0; r0 < ME; r0 += CH) {
            int rows = (ME - r0 < CH) ? (ME - r0) : CH;
            hipLaunchKernelGGL(add_pos_chunk_kernel, dim3((rows * 256 + 255) / 256), dim3(256),
                               0, stream, Xb, POSb, Qh, r0, rows);
            gemm_bf16(Qh, h_enc_offaw + (size_t)i * 73728, enc_oab + i * 288, OAf, rows, 288, 256, 0, 0, stream);
            hipLaunchKernelGGL(msda_kernel, dim3(rows), dim3(256), 0, stream,
                               Vh, OAf, REFEb, OUTh, 0, r0);
            gemm_bf16(OUTh, h_enc_op + (size_t)i * 65536, enc_op_b + i * 256, Yh, rows, 256, 256, 0, 1, stream);
            hipLaunchKernelGGL(ln_res_kernel, dim3((rows + 3) / 4), dim3(256), 0, stream,
                               Xb + (size_t)r0 * 256, Yh, enc_ln1_g + i * 256, enc_ln1_b + i * 256,
                               Xb + (size_t)r0 * 256, Xh + (size_t)r0 * 256, rows);
            gemm_bf16(Xh + (size_t)r0 * 256, h_enc_fc1 + (size_t)i * 262144, enc_fc1_b + i * 1024,
                      HIDh, rows, 1024, 256, 1, 1, stream);
            gemm_bf16(HIDh, h_enc_fc2 + (size_t)i * 262144, enc_fc2_b + i * 256, Yh, rows, 256, 1024, 0, 1, stream);
            hipLaunchKernelGGL(ln_res_kernel, dim3((rows + 3) / 4), dim3(256), 0, stream,
                               Xb + (size_t)r0 * 256, Yh, enc_ln2_g + i * 256, enc_ln2_b + i * 256,
                               Xb + (size_t)r0 * 256, Xh + (size_t)r0 * 256, rows);
        }
    }
    // Xb/Xh now hold `memory`.

    // ---- decoder (state kept in [NQ,BS,D] row order throughout) ----
    for (int i = 0; i < 3; i++) {
        for (int r0 = 0; r0 < MD; r0 += CH) {
            int rows = (MD - r0 < CH) ? (MD - r0) : CH;
            gemm_bf16(TGTh + (size_t)r0 * 256, h_sa_in + (size_t)i * 196608, sa_in_b + i * 768,
                      QKVh, rows, 768, 256, 0, 1, stream);
            hipLaunchKernelGGL(mha_kernel, dim3((rows * 8 + 255) / 256), dim3(256), 0, stream,
                               QKVh, SOh, rows / 8);
            gemm_bf16(SOh, h_sa_out + (size_t)i * 65536, sa_out_b + i * 256, Yh, rows, 256, 256, 0, 1, stream);
            hipLaunchKernelGGL(ln_res_kernel, dim3((rows + 3) / 4), dim3(256), 0, stream,
                               TGTb + (size_t)r0 * 256, Yh, dec_ln2_g + i * 256, dec_ln2_b + i * 256,
                               TGTb + (size_t)r0 * 256, TGTh + (size_t)r0 * 256, rows);
        }
        gemm_bf16(Xh, h_dec_vp + (size_t)i * 65536, dec_vp_b + i * 256, Vh, ME, 256, 256, 0, 1, stream);
        for (int r0 = 0; r0 < MD; r0 += CH) {
            int rows = (MD - r0 < CH) ? (MD - r0) : CH;
            gemm_bf16(TGTh + (size_t)r0 * 256, h_dec_offaw + (size_t)i * 73728, dec_oab + i * 288,
                      OAf, rows, 288, 256, 0, 0, stream);
            hipLaunchKernelGGL(msda_kernel, dim3(rows), dim3(256), 0, stream,
                               Vh, OAf, REFDb, OUTh, 1, r0);
            gemm_bf16(OUTh, h_dec_op + (size_t)i * 65536, dec_op_b + i * 256, Yh, rows, 256, 256, 0, 1, stream);
            hipLaunchKernelGGL(ln_res_kernel, dim3((rows + 3) / 4), dim3(256), 0, stream,
                               TGTb + (size_t)r0 * 256, Yh, dec_ln1_g + i * 256, dec_ln1_b + i * 256,
                               TGTb + (size_t)r0 * 256, TGTh + (size_t)r0 * 256, rows);
            gemm_bf16(TGTh + (size_t)r0 * 256, h_dec_fc1 + (size_t)i * 262144, dec_fc1_b + i * 1024,
                      HIDh, rows, 1024, 256, 1, 1, stream);
            gemm_bf16(HIDh, h_dec_fc2 + (size_t)i * 262144, dec_fc2_b + i * 256, Yh, rows, 256, 1024, 0, 1, stream);
            // last decoder layer writes d_out directly (row order identical)
            float* lnout = (i == 2) ? ((float*)d_out + (size_t)r0 * 256) : (TGTb + (size_t)r0 * 256);
            hipLaunchKernelGGL(ln_res_kernel, dim3((rows + 3) / 4), dim3(256), 0, stream,
                               TGTb + (size_t)r0 * 256, Yh, dec_ln3_g + i * 256, dec_ln3_b + i * 256,
                               lnout, TGTh + (size_t)r0 * 256, rows);
        }
    }
}

// Round 5
// 2842.268 us; speedup vs baseline: 5.1083x; 1.3544x over previous
//
#include <hip/hip_runtime.h>
#include <cmath>

#define D_MODEL 256
#define NHEADS 8
#define BSZ 8
#define S_TOT 4725
#define NQRY 3600
#define CH 19200   // chunk rows

typedef unsigned short ushortT;
using bf16x8  = __attribute__((ext_vector_type(8))) __bf16;
using floatx4 = __attribute__((ext_vector_type(4))) float;

__device__ __forceinline__ ushortT f2bf(float f)
{
    union { float f; unsigned u; } v; v.f = f;
    unsigned r = v.u + 0x7FFFu + ((v.u >> 16) & 1u);
    return (ushortT)(r >> 16);
}
__device__ __forceinline__ float bf2f(ushortT u)
{
    union { unsigned u; float f; } v; v.u = ((unsigned)u) << 16;
    return v.f;
}
__device__ __forceinline__ float bits2f(unsigned u)
{
    union { unsigned u; float f; } v; v.u = u;
    return v.f;
}

#define GLD16(gp, lp) __builtin_amdgcn_global_load_lds( \
    (const __attribute__((address_space(1))) void*)(gp), \
    (__attribute__((address_space(3))) void*)(lp), 16, 0, 0)

// ---------------------------------------------------------------------------
// bf16 MFMA GEMM with async global->LDS staging. (unchanged from round 4)
// ---------------------------------------------------------------------------
template<int RELU, int OUTBF>
__global__ __launch_bounds__(256) void gemm_bf16_kernel(
    const ushortT* __restrict__ A, const ushortT* __restrict__ W,
    const float* __restrict__ bias, void* __restrict__ Cout,
    int M, int N, int K)
{
    __shared__ ushortT As[128 * 32];
    __shared__ ushortT Bs[128 * 32];
    const int tid  = threadIdx.x;
    const int lane = tid & 63;
    const int wid  = tid >> 6;
    const int bm = blockIdx.x * 128;
    const int bn = blockIdx.y * 128;
    const int wm = (wid & 1) * 64;
    const int wn = (wid >> 1) * 64;
    const int col16 = lane & 15;
    const int quad  = lane >> 4;
    const int srow = lane >> 2;
    const int scg  = lane & 3;

    floatx4 acc[4][4];
#pragma unroll
    for (int i = 0; i < 4; i++)
#pragma unroll
        for (int j = 0; j < 4; j++) acc[i][j] = (floatx4){0.f, 0.f, 0.f, 0.f};

    const int rbase = wid * 32;
    for (int k0 = 0; k0 < K; k0 += 32) {
        if (k0) __syncthreads();
#pragma unroll
        for (int j = 0; j < 2; j++) {
            int row = rbase + j * 16 + srow;
            int gm = bm + row; if (gm >= M) gm = M - 1;
            GLD16(A + (size_t)gm * K + k0 + scg * 8, &As[(rbase + j * 16) * 32]);
            int gn = bn + row; if (gn >= N) gn = N - 1;
            GLD16(W + (size_t)gn * K + k0 + scg * 8, &Bs[(rbase + j * 16) * 32]);
        }
        __syncthreads();
        bf16x8 av[4], bv[4];
#pragma unroll
        for (int i = 0; i < 4; i++) {
            av[i] = *(const bf16x8*)&As[(wm + i * 16 + col16) * 32 + quad * 8];
            bv[i] = *(const bf16x8*)&Bs[(wn + i * 16 + col16) * 32 + quad * 8];
        }
#pragma unroll
        for (int mi = 0; mi < 4; mi++)
#pragma unroll
            for (int ni = 0; ni < 4; ni++)
                acc[mi][ni] = __builtin_amdgcn_mfma_f32_16x16x32_bf16(
                    av[mi], bv[ni], acc[mi][ni], 0, 0, 0);
    }

#pragma unroll
    for (int ni = 0; ni < 4; ni++) {
        int gn = bn + wn + ni * 16 + col16;
        if (gn >= N) continue;
        float bs = bias[gn];
#pragma unroll
        for (int mi = 0; mi < 4; mi++) {
#pragma unroll
            for (int r = 0; r < 4; r++) {
                int gm = bm + wm + mi * 16 + quad * 4 + r;
                if (gm >= M) continue;
                float v = acc[mi][ni][r] + bs;
                if (RELU) v = fmaxf(v, 0.f);
                if (OUTBF) ((ushortT*)Cout)[(size_t)gm * N + gn] = f2bf(v);
                else       ((float*)Cout)[(size_t)gm * N + gn] = v;
            }
        }
    }
}

static inline void gemm_bf16(const ushortT* A, const ushortT* W, const float* bias,
                             void* C, int M, int N, int K, int relu, int outbf,
                             hipStream_t s)
{
    dim3 g((M + 127) / 128, (N + 127) / 128);
    if (relu) {
        if (outbf) hipLaunchKernelGGL((gemm_bf16_kernel<1,1>), g, dim3(256), 0, s, A, W, bias, C, M, N, K);
        else       hipLaunchKernelGGL((gemm_bf16_kernel<1,0>), g, dim3(256), 0, s, A, W, bias, C, M, N, K);
    } else {
        if (outbf) hipLaunchKernelGGL((gemm_bf16_kernel<0,1>), g, dim3(256), 0, s, A, W, bias, C, M, N, K);
        else       hipLaunchKernelGGL((gemm_bf16_kernel<0,0>), g, dim3(256), 0, s, A, W, bias, C, M, N, K);
    }
}

// ---------------------------------------------------------------------------
__global__ void f2bf_kernel(const float* __restrict__ src, ushortT* __restrict__ dst, int n)
{
    int t = blockIdx.x * blockDim.x + threadIdx.x;
    if (t < n) dst[t] = f2bf(src[t]);
}

__global__ void conv_offaw_kernel(const float* __restrict__ offW, const float* __restrict__ awW,
                                  ushortT* __restrict__ dst)
{
    int t = blockIdx.x * blockDim.x + threadIdx.x;
    if (t >= 3 * 288 * 256) return;
    int c = t & 255;
    int r = (t >> 8) % 288;
    int i = t / (288 * 256);
    float v = (r < 192) ? offW[((size_t)i * 192 + r) * 256 + c]
                        : awW[((size_t)i * 96 + (r - 192)) * 256 + c];
    dst[t] = f2bf(v);
}

__global__ void conv_offaw_bias_kernel(const float* __restrict__ offb, const float* __restrict__ awb,
                                       float* __restrict__ dst)
{
    int t = blockIdx.x * blockDim.x + threadIdx.x;
    if (t >= 3 * 288) return;
    int r = t % 288;
    int i = t / 288;
    dst[t] = (r < 192) ? offb[i * 192 + r] : awb[i * 96 + (r - 192)];
}

__device__ __forceinline__ void level_of(int s, int& l, int& H, int& W, int& hw)
{
    if (s < 3600)      { l = 0; H = 60; W = 60; hw = s; }
    else if (s < 4500) { l = 1; H = 30; W = 30; hw = s - 3600; }
    else               { l = 2; H = 15; W = 15; hw = s - 4500; }
}

__global__ void build_src_kernel(const float* __restrict__ f0, const float* __restrict__ f1,
                                 const float* __restrict__ f2, float* __restrict__ X,
                                 ushortT* __restrict__ Xh)
{
    int t = blockIdx.x * blockDim.x + threadIdx.x;
    if (t >= BSZ * S_TOT * D_MODEL) return;
    int d = t & 255;
    int r = t >> 8;
    int s = r % S_TOT;
    int b = r / S_TOT;
    int l, H, W, hw; level_of(s, l, H, W, hw);
    const float* f = (l == 0) ? f0 : (l == 1) ? f1 : f2;
    float v = f[((size_t)b * D_MODEL + d) * (size_t)(H * W) + hw];
    X[t] = v;
    Xh[t] = f2bf(v);
}

__global__ void build_pos_kernel(const float* __restrict__ level_embed, float* __restrict__ pos)
{
    int t = blockIdx.x * blockDim.x + threadIdx.x;
    if (t >= S_TOT * D_MODEL) return;
    int d = t & 255;
    int s = t >> 8;
    int l, H, W, hw; level_of(s, l, H, W, hw);
    int y = hw / W, x = hw % W;
    int dd = (d < 128) ? d : d - 128;
    float v = (d < 128)
        ? ((float)(y + 1)) / ((float)H + 1e-6f) * 6.28318530717958647692f
        : ((float)(x + 1)) / ((float)W + 1e-6f) * 6.28318530717958647692f;
    float tpow = powf(10000.f, (float)(2 * (dd >> 1)) * (1.f / 128.f));
    float arg = v / tpow;
    float val = (dd & 1) ? cosf(arg) : sinf(arg);
    pos[t] = val + level_embed[l * D_MODEL + d];
}

__global__ void build_ref_kernel(float* __restrict__ refE, float* __restrict__ refD)
{
    int t = blockIdx.x * blockDim.x + threadIdx.x;
    if (t < S_TOT) {
        int l, H, W, hw; level_of(t, l, H, W, hw);
        int y = hw / W, x = hw % W;
        refE[2 * t]     = ((float)x + 0.5f) / (float)W;
        refE[2 * t + 1] = ((float)y + 0.5f) / (float)H;
    } else if (t < S_TOT + NQRY) {
        int q = t - S_TOT;
        int y = q / 60, x = q % 60;
        refD[2 * q]     = ((float)x + 0.5f) / 60.f;
        refD[2 * q + 1] = ((float)y + 0.5f) / 60.f;
    }
}

__global__ void build_tgt_kernel(const float* __restrict__ context, const float* __restrict__ qe,
                                 float* __restrict__ TGT, ushortT* __restrict__ TGTh)
{
    int t = blockIdx.x * blockDim.x + threadIdx.x;
    if (t >= NQRY * BSZ * D_MODEL) return;
    int d = t & 255;
    int nq = t >> 11;
    float v = context[t] + qe[nq * D_MODEL + d];
    TGT[t] = v;
    TGTh[t] = f2bf(v);
}

__global__ void add_pos_chunk_kernel(const float* __restrict__ X, const float* __restrict__ pos,
                                     ushortT* __restrict__ Qh, int r0, int rows)
{
    int t = blockIdx.x * blockDim.x + threadIdx.x;
    if (t >= rows * D_MODEL) return;
    int d = t & 255;
    int m = r0 + (t >> 8);
    int s = m % S_TOT;
    Qh[t] = f2bf(X[(size_t)m * D_MODEL + d] + pos[(size_t)s * D_MODEL + d]);
}

// ---------------------------------------------------------------------------
// MSDA sampling, vectorized: block = 8 rows; thread = (row, head, chgroup of 8).
// oa staged to LDS; softmax computed once per (row,head) into LDS.
// value bf16 [BSZ,S_TOT,256]; out bf16 [rows,256].
// mode 0 (enc): b=m/S_TOT, q=m%S_TOT.  mode 1 (dec, [NQ,BS] order): q=m>>3, b=m&7.
// ---------------------------------------------------------------------------
#define MROWS 8
__global__ __launch_bounds__(256) void msda_kernel(
    const ushortT* __restrict__ value, const float* __restrict__ oa,
    const float* __restrict__ ref, ushortT* __restrict__ out,
    int mode, int m0, int total_rows)
{
    __shared__ float sOff[MROWS][192];
    __shared__ float sW[MROWS][96];
    const int br0 = blockIdx.x * MROWS;

    for (int idx = threadIdx.x; idx < MROWS * 288; idx += 256) {
        int r = idx / 288, c = idx - r * 288;
        int lm = br0 + r;
        float v = (lm < total_rows) ? oa[(size_t)lm * 288 + c] : 0.f;
        if (c < 192) sOff[r][c] = v;
        else         sW[r][c - 192] = v;
    }
    __syncthreads();
    if (threadIdx.x < 64) {
        int r = threadIdx.x >> 3, h = threadIdx.x & 7;
        float* p = &sW[r][h * 12];
        float mx = p[0];
#pragma unroll
        for (int i = 1; i < 12; i++) mx = fmaxf(mx, p[i]);
        float ssum = 0.f;
        float e[12];
#pragma unroll
        for (int i = 0; i < 12; i++) { e[i] = expf(p[i] - mx); ssum += e[i]; }
        float inv = 1.f / ssum;
#pragma unroll
        for (int i = 0; i < 12; i++) p[i] = e[i] * inv;
    }
    __syncthreads();

    const int r  = threadIdx.x >> 5;        // row within block
    const int h  = (threadIdx.x >> 2) & 7;  // head
    const int cg = threadIdx.x & 3;         // channel group (8 ch)
    const int lm = br0 + r;
    if (lm >= total_rows) return;
    const int m = m0 + lm;
    int b, q;
    if (mode == 0) { b = m / S_TOT; q = m - b * S_TOT; }
    else           { q = m >> 3;    b = m & 7; }
    const float rx = ref[2 * q], ry = ref[2 * q + 1];
    const float* offp = &sOff[r][h * 24];
    const float* wp   = &sW[r][h * 12];

    float acc[8] = {};
    const int HWs[3][3] = {{60, 60, 0}, {30, 30, 3600}, {15, 15, 4500}};
#pragma unroll
    for (int l = 0; l < 3; l++) {
        const int H = HWs[l][0], W = HWs[l][1], s0 = HWs[l][2];
        const ushortT* vbase = value + ((size_t)b * S_TOT + s0) * 256 + h * 32 + cg * 8;
#pragma unroll
        for (int p = 0; p < 4; p++) {
            float ox = offp[(l * 4 + p) * 2];
            float oy = offp[(l * 4 + p) * 2 + 1];
            float w  = wp[l * 4 + p];
            float lx = rx * W + ox - 0.5f;
            float ly = ry * H + oy - 0.5f;
            float x0f = floorf(lx), y0f = floorf(ly);
            int x0 = (int)x0f, y0 = (int)y0f;
            float wx1 = lx - x0f, wy1 = ly - y0f;
            float wx0 = 1.f - wx1, wy0 = 1.f - wy1;
#pragma unroll
            for (int dy = 0; dy < 2; dy++)
#pragma unroll
                for (int dx = 0; dx < 2; dx++) {
                    int xi = x0 + dx, yi = y0 + dy;
                    if (xi >= 0 && xi < W && yi >= 0 && yi < H) {
                        float cw = w * (dx ? wx1 : wx0) * (dy ? wy1 : wy0);
                        uint4 v4 = *(const uint4*)(vbase + (size_t)(yi * W + xi) * 256);
                        acc[0] = fmaf(cw, bits2f(v4.x << 16), acc[0]);
                        acc[1] = fmaf(cw, bits2f(v4.x & 0xFFFF0000u), acc[1]);
                        acc[2] = fmaf(cw, bits2f(v4.y << 16), acc[2]);
                        acc[3] = fmaf(cw, bits2f(v4.y & 0xFFFF0000u), acc[3]);
                        acc[4] = fmaf(cw, bits2f(v4.z << 16), acc[4]);
                        acc[5] = fmaf(cw, bits2f(v4.z & 0xFFFF0000u), acc[5]);
                        acc[6] = fmaf(cw, bits2f(v4.w << 16), acc[6]);
                        acc[7] = fmaf(cw, bits2f(v4.w & 0xFFFF0000u), acc[7]);
                    }
                }
        }
    }
    ushortT pk[8];
#pragma unroll
    for (int i = 0; i < 8; i++) pk[i] = f2bf(acc[i]);
    *(uint4*)(out + (size_t)lm * 256 + h * 32 + cg * 8) = *(uint4*)pk;
}

// out = LayerNorm(x + a) * g + b; a is bf16; writes fp32 out + bf16 mirror
__global__ void ln_res_kernel(const float* __restrict__ x, const ushortT* __restrict__ a,
                              const float* __restrict__ g, const float* __restrict__ b,
                              float* __restrict__ out, ushortT* __restrict__ outh, int M)
{
    int wave = threadIdx.x >> 6;
    int lane = threadIdx.x & 63;
    int row = blockIdx.x * 4 + wave;
    if (row >= M) return;
    const float* xp = x + (size_t)row * 256;
    const ushortT* ap = a + (size_t)row * 256;
    float v[4];
    float s = 0.f;
#pragma unroll
    for (int i = 0; i < 4; i++) { v[i] = xp[lane + i * 64] + bf2f(ap[lane + i * 64]); s += v[i]; }
#pragma unroll
    for (int o = 32; o > 0; o >>= 1) s += __shfl_down(s, o);
    s = __shfl(s, 0);
    float mean = s * (1.f / 256.f);
    float vs = 0.f;
#pragma unroll
    for (int i = 0; i < 4; i++) { float d = v[i] - mean; vs += d * d; }
#pragma unroll
    for (int o = 32; o > 0; o >>= 1) vs += __shfl_down(vs, o);
    vs = __shfl(vs, 0);
    float inv = rsqrtf(vs * (1.f / 256.f) + 1e-5f);
    float* op = out + (size_t)row * 256;
    ushortT* oh = outh + (size_t)row * 256;
#pragma unroll
    for (int i = 0; i < 4; i++) {
        int d = lane + i * 64;
        float val = (v[i] - mean) * inv * g[d] + b[d];
        op[d] = val;
        oh[d] = f2bf(val);
    }
}

// Decoder self-attn over L=8 (batch). qkv bf16 chunk rows n_local*8+l; out bf16.
__global__ void mha_kernel(const ushortT* __restrict__ qkv, ushortT* __restrict__ o, int nCnt)
{
    int t = blockIdx.x * blockDim.x + threadIdx.x;
    if (t >= nCnt * 64) return;
    int l = t & 7;
    int h = (t >> 3) & 7;
    int n = t >> 6;
    const ushortT* qp = qkv + (size_t)(n * 8 + l) * 768 + h * 32;
    float q[32];
#pragma unroll
    for (int d = 0; d < 32; d++) q[d] = bf2f(qp[d]);
    float sc[8];
#pragma unroll
    for (int s = 0; s < 8; s++) {
        const ushortT* kp = qkv + (size_t)(n * 8 + s) * 768 + 256 + h * 32;
        float acc = 0.f;
#pragma unroll
        for (int d = 0; d < 32; d++) acc = fmaf(q[d], bf2f(kp[d]), acc);
        sc[s] = acc * 0.17677669529663688f;
    }
    float mx = sc[0];
#pragma unroll
    for (int s = 1; s < 8; s++) mx = fmaxf(mx, sc[s]);
    float sum = 0.f;
#pragma unroll
    for (int s = 0; s < 8; s++) { sc[s] = expf(sc[s] - mx); sum += sc[s]; }
    float inv = 1.f / sum;
    float outv[32] = {};
#pragma unroll
    for (int s = 0; s < 8; s++) {
        const ushortT* vp = qkv + (size_t)(n * 8 + s) * 768 + 512 + h * 32;
        float a = sc[s] * inv;
#pragma unroll
        for (int d = 0; d < 32; d++) outv[d] = fmaf(a, bf2f(vp[d]), outv[d]);
    }
    ushortT* op = o + (size_t)(n * 8 + l) * 256 + h * 32;
#pragma unroll
    for (int d = 0; d < 32; d++) op[d] = f2bf(outv[d]);
}

// ---------------------------------------------------------------------------
extern "C" void kernel_launch(void* const* d_in, const int* in_sizes, int n_in,
                              void* d_out, int out_size, void* d_ws, size_t ws_size,
                              hipStream_t stream)
{
    const float* feat0       = (const float*)d_in[0];
    const float* feat1       = (const float*)d_in[1];
    const float* feat2       = (const float*)d_in[2];
    const float* context     = (const float*)d_in[3];
    const float* query_embed = (const float*)d_in[4];
    const float* level_embed = (const float*)d_in[5];
    const float* enc_off_W = (const float*)d_in[6];
    const float* enc_off_b = (const float*)d_in[7];
    const float* enc_aw_W  = (const float*)d_in[8];
    const float* enc_aw_b  = (const float*)d_in[9];
    const float* enc_vp_W  = (const float*)d_in[10];
    const float* enc_vp_b  = (const float*)d_in[11];
    const float* enc_op_W  = (const float*)d_in[12];
    const float* enc_op_b  = (const float*)d_in[13];
    const float* enc_fc1_W = (const float*)d_in[14];
    const float* enc_fc1_b = (const float*)d_in[15];
    const float* enc_fc2_W = (const float*)d_in[16];
    const float* enc_fc2_b = (const float*)d_in[17];
    const float* enc_ln1_g = (const float*)d_in[18];
    const float* enc_ln1_b = (const float*)d_in[19];
    const float* enc_ln2_g = (const float*)d_in[20];
    const float* enc_ln2_b = (const float*)d_in[21];
    const float* dec_off_W = (const float*)d_in[22];
    const float* dec_off_b = (const float*)d_in[23];
    const float* dec_aw_W  = (const float*)d_in[24];
    const float* dec_aw_b  = (const float*)d_in[25];
    const float* dec_vp_W  = (const float*)d_in[26];
    const float* dec_vp_b  = (const float*)d_in[27];
    const float* dec_op_W  = (const float*)d_in[28];
    const float* dec_op_b  = (const float*)d_in[29];
    const float* dec_fc1_W = (const float*)d_in[30];
    const float* dec_fc1_b = (const float*)d_in[31];
    const float* dec_fc2_W = (const float*)d_in[32];
    const float* dec_fc2_b = (const float*)d_in[33];
    const float* dec_ln1_g = (const float*)d_in[34];
    const float* dec_ln1_b = (const float*)d_in[35];
    const float* dec_ln2_g = (const float*)d_in[36];
    const float* dec_ln2_b = (const float*)d_in[37];
    const float* sa_in_W   = (const float*)d_in[38];
    const float* sa_in_b   = (const float*)d_in[39];
    const float* sa_out_W  = (const float*)d_in[40];
    const float* sa_out_b  = (const float*)d_in[41];
    const float* dec_ln3_g = (const float*)d_in[42];
    const float* dec_ln3_b = (const float*)d_in[43];

    const int ME = BSZ * S_TOT;       // 37800
    const int MD = BSZ * NQRY;        // 28800
    const int EW = ME * D_MODEL;      // 9,676,800
    const int DW = MD * D_MODEL;      // 7,372,800

    char* base = (char*)d_ws;
    size_t off = 0;
    auto alloc = [&](size_t bytes) -> char* {
        char* p = base + off;
        off += (bytes + 255) & ~(size_t)255;
        return p;
    };
    float*   Xb    = (float*)alloc((size_t)EW * 4);
    float*   TGTb  = (float*)alloc((size_t)DW * 4);
    float*   POSb  = (float*)alloc((size_t)S_TOT * 256 * 4);
    float*   REFEb = (float*)alloc((size_t)S_TOT * 2 * 4);
    float*   REFDb = (float*)alloc((size_t)NQRY * 2 * 4);
    ushortT* Xh    = (ushortT*)alloc((size_t)EW * 2);
    ushortT* Vh    = (ushortT*)alloc((size_t)EW * 2);
    ushortT* TGTh  = (ushortT*)alloc((size_t)DW * 2);
    ushortT* Wbf   = (ushortT*)alloc((size_t)5160960 * 2);
    float*   OBIAS = (float*)alloc((size_t)2 * 3 * 288 * 4);
    char*    R     = alloc((size_t)41779200);
    ushortT* Yh    = (ushortT*)alloc((size_t)CH * 256 * 2);
    if (ws_size < off) return;

    ushortT* Qh   = (ushortT*)R;                      // [CH,256] bf16
    float*   OAf  = (float*)(R + 9830400);            // [CH,288] f32
    ushortT* OUTh = (ushortT*)(R + 31948800);         // [CH,256] bf16
    ushortT* QKVh = (ushortT*)R;                      // [CH,768] bf16
    ushortT* SOh  = (ushortT*)(R + 29491200);         // [CH,256] bf16
    ushortT* HIDh = (ushortT*)R;                      // [CH,1024] bf16

    size_t wo = 0;
    auto walloc = [&](size_t elems) -> ushortT* { ushortT* p = Wbf + wo; wo += elems; return p; };
    ushortT* h_enc_offaw = walloc(3 * 288 * 256);
    ushortT* h_enc_vp    = walloc(3 * 65536);
    ushortT* h_enc_op    = walloc(3 * 65536);
    ushortT* h_enc_fc1   = walloc(3 * 262144);
    ushortT* h_enc_fc2   = walloc(3 * 262144);
    ushortT* h_dec_offaw = walloc(3 * 288 * 256);
    ushortT* h_dec_vp    = walloc(3 * 65536);
    ushortT* h_dec_op    = walloc(3 * 65536);
    ushortT* h_dec_fc1   = walloc(3 * 262144);
    ushortT* h_dec_fc2   = walloc(3 * 262144);
    ushortT* h_sa_in     = walloc(3 * 196608);
    ushortT* h_sa_out    = walloc(3 * 65536);
    float* enc_oab = OBIAS;
    float* dec_oab = OBIAS + 3 * 288;

    auto conv = [&](const float* s, ushortT* d, int n) {
        hipLaunchKernelGGL(f2bf_kernel, dim3((n + 255) / 256), dim3(256), 0, stream, s, d, n);
    };
    hipLaunchKernelGGL(conv_offaw_kernel, dim3((3 * 288 * 256 + 255) / 256), dim3(256), 0, stream,
                       enc_off_W, enc_aw_W, h_enc_offaw);
    hipLaunchKernelGGL(conv_offaw_kernel, dim3((3 * 288 * 256 + 255) / 256), dim3(256), 0, stream,
                       dec_off_W, dec_aw_W, h_dec_offaw);
    hipLaunchKernelGGL(conv_offaw_bias_kernel, dim3(4), dim3(256), 0, stream,
                       enc_off_b, enc_aw_b, enc_oab);
    hipLaunchKernelGGL(conv_offaw_bias_kernel, dim3(4), dim3(256), 0, stream,
                       dec_off_b, dec_aw_b, dec_oab);
    conv(enc_vp_W,  h_enc_vp,  3 * 65536);
    conv(enc_op_W,  h_enc_op,  3 * 65536);
    conv(enc_fc1_W, h_enc_fc1, 3 * 262144);
    conv(enc_fc2_W, h_enc_fc2, 3 * 262144);
    conv(dec_vp_W,  h_dec_vp,  3 * 65536);
    conv(dec_op_W,  h_dec_op,  3 * 65536);
    conv(dec_fc1_W, h_dec_fc1, 3 * 262144);
    conv(dec_fc2_W, h_dec_fc2, 3 * 262144);
    conv(sa_in_W,   h_sa_in,   3 * 196608);
    conv(sa_out_W,  h_sa_out,  3 * 65536);

    hipLaunchKernelGGL(build_pos_kernel, dim3((S_TOT * 256 + 255) / 256), dim3(256), 0, stream,
                       level_embed, POSb);
    hipLaunchKernelGGL(build_ref_kernel, dim3((S_TOT + NQRY + 255) / 256), dim3(256), 0, stream,
                       REFEb, REFDb);
    hipLaunchKernelGGL(build_src_kernel, dim3((EW + 255) / 256), dim3(256), 0, stream,
                       feat0, feat1, feat2, Xb, Xh);
    hipLaunchKernelGGL(build_tgt_kernel, dim3((DW + 255) / 256), dim3(256), 0, stream,
                       context, query_embed, TGTb, TGTh);

    // ---- encoder ----
    for (int i = 0; i < 3; i++) {
        gemm_bf16(Xh, h_enc_vp + (size_t)i * 65536, enc_vp_b + i * 256, Vh, ME, 256, 256, 0, 1, stream);
        for (int r0 = 0; r0 < ME; r0 += CH) {
            int rows = (ME - r0 < CH) ? (ME - r0) : CH;
            hipLaunchKernelGGL(add_pos_chunk_kernel, dim3((rows * 256 + 255) / 256), dim3(256),
                               0, stream, Xb, POSb, Qh, r0, rows);
            gemm_bf16(Qh, h_enc_offaw + (size_t)i * 73728, enc_oab + i * 288, OAf, rows, 288, 256, 0, 0, stream);
            hipLaunchKernelGGL(msda_kernel, dim3((rows + MROWS - 1) / MROWS), dim3(256), 0, stream,
                               Vh, OAf, REFEb, OUTh, 0, r0, rows);
            gemm_bf16(OUTh, h_enc_op + (size_t)i * 65536, enc_op_b + i * 256, Yh, rows, 256, 256, 0, 1, stream);
            hipLaunchKernelGGL(ln_res_kernel, dim3((rows + 3) / 4), dim3(256), 0, stream,
                               Xb + (size_t)r0 * 256, Yh, enc_ln1_g + i * 256, enc_ln1_b + i * 256,
                               Xb + (size_t)r0 * 256, Xh + (size_t)r0 * 256, rows);
            gemm_bf16(Xh + (size_t)r0 * 256, h_enc_fc1 + (size_t)i * 262144, enc_fc1_b + i * 1024,
                      HIDh, rows, 1024, 256, 1, 1, stream);
            gemm_bf16(HIDh, h_enc_fc2 + (size_t)i * 262144, enc_fc2_b + i * 256, Yh, rows, 256, 1024, 0, 1, stream);
            hipLaunchKernelGGL(ln_res_kernel, dim3((rows + 3) / 4), dim3(256), 0, stream,
                               Xb + (size_t)r0 * 256, Yh, enc_ln2_g + i * 256, enc_ln2_b + i * 256,
                               Xb + (size_t)r0 * 256, Xh + (size_t)r0 * 256, rows);
        }
    }

    // ---- decoder ----
    for (int i = 0; i < 3; i++) {
        for (int r0 = 0; r0 < MD; r0 += CH) {
            int rows = (MD - r0 < CH) ? (MD - r0) : CH;
            gemm_bf16(TGTh + (size_t)r0 * 256, h_sa_in + (size_t)i * 196608, sa_in_b + i * 768,
                      QKVh, rows, 768, 256, 0, 1, stream);
            hipLaunchKernelGGL(mha_kernel, dim3((rows * 8 + 255) / 256), dim3(256), 0, stream,
                               QKVh, SOh, rows / 8);
            gemm_bf16(SOh, h_sa_out + (size_t)i * 65536, sa_out_b + i * 256, Yh, rows, 256, 256, 0, 1, stream);
            hipLaunchKernelGGL(ln_res_kernel, dim3((rows + 3) / 4), dim3(256), 0, stream,
                               TGTb + (size_t)r0 * 256, Yh, dec_ln2_g + i * 256, dec_ln2_b + i * 256,
                               TGTb + (size_t)r0 * 256, TGTh + (size_t)r0 * 256, rows);
        }
        gemm_bf16(Xh, h_dec_vp + (size_t)i * 65536, dec_vp_b + i * 256, Vh, ME, 256, 256, 0, 1, stream);
        for (int r0 = 0; r0 < MD; r0 += CH) {
            int rows = (MD - r0 < CH) ? (MD - r0) : CH;
            gemm_bf16(TGTh + (size_t)r0 * 256, h_dec_offaw + (size_t)i * 73728, dec_oab + i * 288,
                      OAf, rows, 288, 256, 0, 0, stream);
            hipLaunchKernelGGL(msda_kernel, dim3((rows + MROWS - 1) / MROWS), dim3(256), 0, stream,
                               Vh, OAf, REFDb, OUTh, 1, r0, rows);
            gemm_bf16(OUTh, h_dec_op + (size_t)i * 65536, dec_op_b + i * 256, Yh, rows, 256, 256, 0, 1, stream);
            hipLaunchKernelGGL(ln_res_kernel, dim3((rows + 3) / 4), dim3(256), 0, stream,
                               TGTb + (size_t)r0 * 256, Yh, dec_ln1_g + i * 256, dec_ln1_b + i * 256,
                               TGTb + (size_t)r0 * 256, TGTh + (size_t)r0 * 256, rows);
            gemm_bf16(TGTh + (size_t)r0 * 256, h_dec_fc1 + (size_t)i * 262144, dec_fc1_b + i * 1024,
                      HIDh, rows, 1024, 256, 1, 1, stream);
            gemm_bf16(HIDh, h_dec_fc2 + (size_t)i * 262144, dec_fc2_b + i * 256, Yh, rows, 256, 1024, 0, 1, stream);
            float* lnout = (i == 2) ? ((float*)d_out + (size_t)r0 * 256) : (TGTb + (size_t)r0 * 256);
            hipLaunchKernelGGL(ln_res_kernel, dim3((rows + 3) / 4), dim3(256), 0, stream,
                               TGTb + (size_t)r0 * 256, Yh, dec_ln3_g + i * 256, dec_ln3_b + i * 256,
                               lnout, TGTh + (size_t)r0 * 256, rows);
        }
    }
}

// Round 6
// 2027.208 us; speedup vs baseline: 7.1622x; 1.4021x over previous
//
#include <hip/hip_runtime.h>
#include <cmath>

#define D_MODEL 256
#define NHEADS 8
#define BSZ 8
#define S_TOT 4725
#define NQRY 3600

typedef unsigned short ushortT;
using bf16x8  = __attribute__((ext_vector_type(8))) __bf16;
using floatx4 = __attribute__((ext_vector_type(4))) float;

__device__ __forceinline__ ushortT f2bf(float f)
{
    union { float f; unsigned u; } v; v.f = f;
    unsigned r = v.u + 0x7FFFu + ((v.u >> 16) & 1u);
    return (ushortT)(r >> 16);
}
__device__ __forceinline__ float bf2f(ushortT u)
{
    union { unsigned u; float f; } v; v.u = ((unsigned)u) << 16;
    return v.f;
}
__device__ __forceinline__ float bits2f(unsigned u)
{
    union { unsigned u; float f; } v; v.u = u;
    return v.f;
}

#define GLD16(gp, lp) __builtin_amdgcn_global_load_lds( \
    (const __attribute__((address_space(1))) void*)(gp), \
    (__attribute__((address_space(3))) void*)(lp), 16, 0, 0)

// ---------------------------------------------------------------------------
// bf16 MFMA GEMM with async global->LDS staging. (unchanged)
// ---------------------------------------------------------------------------
template<int RELU, int OUTBF>
__global__ __launch_bounds__(256) void gemm_bf16_kernel(
    const ushortT* __restrict__ A, const ushortT* __restrict__ W,
    const float* __restrict__ bias, void* __restrict__ Cout,
    int M, int N, int K)
{
    __shared__ ushortT As[128 * 32];
    __shared__ ushortT Bs[128 * 32];
    const int tid  = threadIdx.x;
    const int lane = tid & 63;
    const int wid  = tid >> 6;
    const int bm = blockIdx.x * 128;
    const int bn = blockIdx.y * 128;
    const int wm = (wid & 1) * 64;
    const int wn = (wid >> 1) * 64;
    const int col16 = lane & 15;
    const int quad  = lane >> 4;
    const int srow = lane >> 2;
    const int scg  = lane & 3;

    floatx4 acc[4][4];
#pragma unroll
    for (int i = 0; i < 4; i++)
#pragma unroll
        for (int j = 0; j < 4; j++) acc[i][j] = (floatx4){0.f, 0.f, 0.f, 0.f};

    const int rbase = wid * 32;
    for (int k0 = 0; k0 < K; k0 += 32) {
        if (k0) __syncthreads();
#pragma unroll
        for (int j = 0; j < 2; j++) {
            int row = rbase + j * 16 + srow;
            int gm = bm + row; if (gm >= M) gm = M - 1;
            GLD16(A + (size_t)gm * K + k0 + scg * 8, &As[(rbase + j * 16) * 32]);
            int gn = bn + row; if (gn >= N) gn = N - 1;
            GLD16(W + (size_t)gn * K + k0 + scg * 8, &Bs[(rbase + j * 16) * 32]);
        }
        __syncthreads();
        bf16x8 av[4], bv[4];
#pragma unroll
        for (int i = 0; i < 4; i++) {
            av[i] = *(const bf16x8*)&As[(wm + i * 16 + col16) * 32 + quad * 8];
            bv[i] = *(const bf16x8*)&Bs[(wn + i * 16 + col16) * 32 + quad * 8];
        }
#pragma unroll
        for (int mi = 0; mi < 4; mi++)
#pragma unroll
            for (int ni = 0; ni < 4; ni++)
                acc[mi][ni] = __builtin_amdgcn_mfma_f32_16x16x32_bf16(
                    av[mi], bv[ni], acc[mi][ni], 0, 0, 0);
    }

#pragma unroll
    for (int ni = 0; ni < 4; ni++) {
        int gn = bn + wn + ni * 16 + col16;
        if (gn >= N) continue;
        float bs = bias[gn];
#pragma unroll
        for (int mi = 0; mi < 4; mi++) {
#pragma unroll
            for (int r = 0; r < 4; r++) {
                int gm = bm + wm + mi * 16 + quad * 4 + r;
                if (gm >= M) continue;
                float v = acc[mi][ni][r] + bs;
                if (RELU) v = fmaxf(v, 0.f);
                if (OUTBF) ((ushortT*)Cout)[(size_t)gm * N + gn] = f2bf(v);
                else       ((float*)Cout)[(size_t)gm * N + gn] = v;
            }
        }
    }
}

static inline void gemm_bf16(const ushortT* A, const ushortT* W, const float* bias,
                             void* C, int M, int N, int K, int relu, int outbf,
                             hipStream_t s)
{
    dim3 g((M + 127) / 128, (N + 127) / 128);
    if (relu) {
        if (outbf) hipLaunchKernelGGL((gemm_bf16_kernel<1,1>), g, dim3(256), 0, s, A, W, bias, C, M, N, K);
        else       hipLaunchKernelGGL((gemm_bf16_kernel<1,0>), g, dim3(256), 0, s, A, W, bias, C, M, N, K);
    } else {
        if (outbf) hipLaunchKernelGGL((gemm_bf16_kernel<0,1>), g, dim3(256), 0, s, A, W, bias, C, M, N, K);
        else       hipLaunchKernelGGL((gemm_bf16_kernel<0,0>), g, dim3(256), 0, s, A, W, bias, C, M, N, K);
    }
}

// ---------------------------------------------------------------------------
__global__ void f2bf_kernel(const float* __restrict__ src, ushortT* __restrict__ dst, int n)
{
    int t = blockIdx.x * blockDim.x + threadIdx.x;
    if (t < n) dst[t] = f2bf(src[t]);
}

__global__ void conv_offaw_kernel(const float* __restrict__ offW, const float* __restrict__ awW,
                                  ushortT* __restrict__ dst)
{
    int t = blockIdx.x * blockDim.x + threadIdx.x;
    if (t >= 3 * 288 * 256) return;
    int c = t & 255;
    int r = (t >> 8) % 288;
    int i = t / (288 * 256);
    float v = (r < 192) ? offW[((size_t)i * 192 + r) * 256 + c]
                        : awW[((size_t)i * 96 + (r - 192)) * 256 + c];
    dst[t] = f2bf(v);
}

__global__ void conv_offaw_bias_kernel(const float* __restrict__ offb, const float* __restrict__ awb,
                                       float* __restrict__ dst)
{
    int t = blockIdx.x * blockDim.x + threadIdx.x;
    if (t >= 3 * 288) return;
    int r = t % 288;
    int i = t / 288;
    dst[t] = (r < 192) ? offb[i * 192 + r] : awb[i * 96 + (r - 192)];
}

__device__ __forceinline__ void level_of(int s, int& l, int& H, int& W, int& hw)
{
    if (s < 3600)      { l = 0; H = 60; W = 60; hw = s; }
    else if (s < 4500) { l = 1; H = 30; W = 30; hw = s - 3600; }
    else               { l = 2; H = 15; W = 15; hw = s - 4500; }
}

// ---------------------------------------------------------------------------
// LDS-tiled transpose: f[b][d0+.][hw] (fp32) -> Xh[b][s0+hw][d0+.] (bf16)
// Coalesced on both global read (along hw) and global write (along d).
// ---------------------------------------------------------------------------
__global__ __launch_bounds__(256) void transpose_feat_kernel(
    const float* __restrict__ f, ushortT* __restrict__ Xh, int HW, int s0)
{
    __shared__ float tile[32][33];
    const int b  = blockIdx.z;
    const int hw0 = blockIdx.x * 32;
    const int d0  = blockIdx.y * 32;
    const int tx = threadIdx.x & 31;
    const int ty = threadIdx.x >> 5;   // 0..7
    const float* fb = f + ((size_t)b * 256 + d0) * HW + hw0;
#pragma unroll
    for (int r = ty; r < 32; r += 8) {
        if (hw0 + tx < HW) tile[r][tx] = fb[(size_t)r * HW + tx];
    }
    __syncthreads();
    ushortT* xb = Xh + ((size_t)b * S_TOT + s0 + hw0) * 256 + d0;
#pragma unroll
    for (int r = ty; r < 32; r += 8) {
        if (hw0 + r < HW) xb[(size_t)r * 256 + tx] = f2bf(tile[tx][r]);
    }
}

__global__ void build_pos_kernel(const float* __restrict__ level_embed, float* __restrict__ pos)
{
    int t = blockIdx.x * blockDim.x + threadIdx.x;
    if (t >= S_TOT * D_MODEL) return;
    int d = t & 255;
    int s = t >> 8;
    int l, H, W, hw; level_of(s, l, H, W, hw);
    int y = hw / W, x = hw % W;
    int dd = (d < 128) ? d : d - 128;
    float v = (d < 128)
        ? ((float)(y + 1)) / ((float)H + 1e-6f) * 6.28318530717958647692f
        : ((float)(x + 1)) / ((float)W + 1e-6f) * 6.28318530717958647692f;
    float tpow = powf(10000.f, (float)(2 * (dd >> 1)) * (1.f / 128.f));
    float arg = v / tpow;
    float val = (dd & 1) ? cosf(arg) : sinf(arg);
    pos[t] = val + level_embed[l * D_MODEL + d];
}

__global__ void build_ref_kernel(float* __restrict__ refE, float* __restrict__ refD)
{
    int t = blockIdx.x * blockDim.x + threadIdx.x;
    if (t < S_TOT) {
        int l, H, W, hw; level_of(t, l, H, W, hw);
        int y = hw / W, x = hw % W;
        refE[2 * t]     = ((float)x + 0.5f) / (float)W;
        refE[2 * t + 1] = ((float)y + 0.5f) / (float)H;
    } else if (t < S_TOT + NQRY) {
        int q = t - S_TOT;
        int y = q / 60, x = q % 60;
        refD[2 * q]     = ((float)x + 0.5f) / 60.f;
        refD[2 * q + 1] = ((float)y + 0.5f) / 60.f;
    }
}

// tgt bf16 [NQ,BS,D] = bf16(context + query_embed); 4 elems/thread
__global__ void build_tgt_kernel(const float* __restrict__ context, const float* __restrict__ qe,
                                 ushortT* __restrict__ TGTh)
{
    int t = blockIdx.x * blockDim.x + threadIdx.x;
    if (t >= NQRY * BSZ * 64) return;
    int gi = t & 63;
    int row = t >> 6;
    int nq = row >> 3;
    int d0 = gi * 4;
    const float4 c4 = *(const float4*)(context + (size_t)row * 256 + d0);
    const float4 q4 = *(const float4*)(qe + (size_t)nq * 256 + d0);
    ushortT pk[4] = { f2bf(c4.x + q4.x), f2bf(c4.y + q4.y), f2bf(c4.z + q4.z), f2bf(c4.w + q4.w) };
    *(uint2*)(TGTh + (size_t)row * 256 + d0) = *(uint2*)pk;
}

// Qh = bf16(Xh + pos[row % S_TOT]); 4 elems/thread
__global__ void add_pos_kernel(const ushortT* __restrict__ Xh, const float* __restrict__ pos,
                               ushortT* __restrict__ Qh)
{
    int t = blockIdx.x * blockDim.x + threadIdx.x;
    if (t >= BSZ * S_TOT * 64) return;
    int gi = t & 63;
    int row = t >> 6;
    int s = row % S_TOT;
    int d0 = gi * 4;
    ushortT x4[4];
    *(uint2*)x4 = *(const uint2*)(Xh + (size_t)row * 256 + d0);
    const float4 p4 = *(const float4*)(pos + (size_t)s * 256 + d0);
    ushortT pk[4] = { f2bf(bf2f(x4[0]) + p4.x), f2bf(bf2f(x4[1]) + p4.y),
                      f2bf(bf2f(x4[2]) + p4.z), f2bf(bf2f(x4[3]) + p4.w) };
    *(uint2*)(Qh + (size_t)row * 256 + d0) = *(uint2*)pk;
}

// ---------------------------------------------------------------------------
// MSDA sampling (unchanged structure): block = 8 rows; thread = (row, head, cg).
// ---------------------------------------------------------------------------
#define MROWS 8
__global__ __launch_bounds__(256) void msda_kernel(
    const ushortT* __restrict__ value, const float* __restrict__ oa,
    const float* __restrict__ ref, ushortT* __restrict__ out,
    int mode, int total_rows)
{
    __shared__ float sOff[MROWS][192];
    __shared__ float sW[MROWS][96];
    const int br0 = blockIdx.x * MROWS;

    for (int idx = threadIdx.x; idx < MROWS * 288; idx += 256) {
        int r = idx / 288, c = idx - r * 288;
        int lm = br0 + r;
        float v = (lm < total_rows) ? oa[(size_t)lm * 288 + c] : 0.f;
        if (c < 192) sOff[r][c] = v;
        else         sW[r][c - 192] = v;
    }
    __syncthreads();
    if (threadIdx.x < 64) {
        int r = threadIdx.x >> 3, h = threadIdx.x & 7;
        float* p = &sW[r][h * 12];
        float mx = p[0];
#pragma unroll
        for (int i = 1; i < 12; i++) mx = fmaxf(mx, p[i]);
        float ssum = 0.f;
        float e[12];
#pragma unroll
        for (int i = 0; i < 12; i++) { e[i] = expf(p[i] - mx); ssum += e[i]; }
        float inv = 1.f / ssum;
#pragma unroll
        for (int i = 0; i < 12; i++) p[i] = e[i] * inv;
    }
    __syncthreads();

    const int r  = threadIdx.x >> 5;
    const int h  = (threadIdx.x >> 2) & 7;
    const int cg = threadIdx.x & 3;
    const int lm = br0 + r;
    if (lm >= total_rows) return;
    int b, q;
    if (mode == 0) { b = lm / S_TOT; q = lm - b * S_TOT; }
    else           { q = lm >> 3;    b = lm & 7; }
    const float rx = ref[2 * q], ry = ref[2 * q + 1];
    const float* offp = &sOff[r][h * 24];
    const float* wp   = &sW[r][h * 12];

    float acc[8] = {};
    const int HWs[3][3] = {{60, 60, 0}, {30, 30, 3600}, {15, 15, 4500}};
#pragma unroll
    for (int l = 0; l < 3; l++) {
        const int H = HWs[l][0], W = HWs[l][1], s0 = HWs[l][2];
        const ushortT* vbase = value + ((size_t)b * S_TOT + s0) * 256 + h * 32 + cg * 8;
#pragma unroll
        for (int p = 0; p < 4; p++) {
            float ox = offp[(l * 4 + p) * 2];
            float oy = offp[(l * 4 + p) * 2 + 1];
            float w  = wp[l * 4 + p];
            float lx = rx * W + ox - 0.5f;
            float ly = ry * H + oy - 0.5f;
            float x0f = floorf(lx), y0f = floorf(ly);
            int x0 = (int)x0f, y0 = (int)y0f;
            float wx1 = lx - x0f, wy1 = ly - y0f;
            float wx0 = 1.f - wx1, wy0 = 1.f - wy1;
#pragma unroll
            for (int dy = 0; dy < 2; dy++)
#pragma unroll
                for (int dx = 0; dx < 2; dx++) {
                    int xi = x0 + dx, yi = y0 + dy;
                    if (xi >= 0 && xi < W && yi >= 0 && yi < H) {
                        float cw = w * (dx ? wx1 : wx0) * (dy ? wy1 : wy0);
                        uint4 v4 = *(const uint4*)(vbase + (size_t)(yi * W + xi) * 256);
                        acc[0] = fmaf(cw, bits2f(v4.x << 16), acc[0]);
                        acc[1] = fmaf(cw, bits2f(v4.x & 0xFFFF0000u), acc[1]);
                        acc[2] = fmaf(cw, bits2f(v4.y << 16), acc[2]);
                        acc[3] = fmaf(cw, bits2f(v4.y & 0xFFFF0000u), acc[3]);
                        acc[4] = fmaf(cw, bits2f(v4.z << 16), acc[4]);
                        acc[5] = fmaf(cw, bits2f(v4.z & 0xFFFF0000u), acc[5]);
                        acc[6] = fmaf(cw, bits2f(v4.w << 16), acc[6]);
                        acc[7] = fmaf(cw, bits2f(v4.w & 0xFFFF0000u), acc[7]);
                    }
                }
        }
    }
    ushortT pk[8];
#pragma unroll
    for (int i = 0; i < 8; i++) pk[i] = f2bf(acc[i]);
    *(uint4*)(out + (size_t)lm * 256 + h * 32 + cg * 8) = *(uint4*)pk;
}

// ---------------------------------------------------------------------------
// LN over bf16 residual stream: out = LayerNorm(x + a) * g + b.
// x,a bf16; stats in fp32; writes bf16 outh (+ fp32 outf if non-null).
// One wave per 256-wide row, 4 elems/lane, vectorized loads. In-place safe.
// ---------------------------------------------------------------------------
__global__ void ln_res_kernel(const ushortT* __restrict__ x, const ushortT* __restrict__ a,
                              const float* __restrict__ g, const float* __restrict__ b,
                              ushortT* __restrict__ outh, float* __restrict__ outf, int M)
{
    int wave = threadIdx.x >> 6;
    int lane = threadIdx.x & 63;
    int row = blockIdx.x * 4 + wave;
    if (row >= M) return;
    const int d0 = lane * 4;
    ushortT x4[4], a4[4];
    *(uint2*)x4 = *(const uint2*)(x + (size_t)row * 256 + d0);
    *(uint2*)a4 = *(const uint2*)(a + (size_t)row * 256 + d0);
    float v[4];
    float s = 0.f;
#pragma unroll
    for (int i = 0; i < 4; i++) { v[i] = bf2f(x4[i]) + bf2f(a4[i]); s += v[i]; }
#pragma unroll
    for (int o = 32; o > 0; o >>= 1) s += __shfl_down(s, o);
    s = __shfl(s, 0);
    float mean = s * (1.f / 256.f);
    float vs = 0.f;
#pragma unroll
    for (int i = 0; i < 4; i++) { float d = v[i] - mean; vs += d * d; }
#pragma unroll
    for (int o = 32; o > 0; o >>= 1) vs += __shfl_down(vs, o);
    vs = __shfl(vs, 0);
    float inv = rsqrtf(vs * (1.f / 256.f) + 1e-5f);
    const float4 g4 = *(const float4*)(g + d0);
    const float4 b4 = *(const float4*)(b + d0);
    float o0 = (v[0] - mean) * inv * g4.x + b4.x;
    float o1 = (v[1] - mean) * inv * g4.y + b4.y;
    float o2 = (v[2] - mean) * inv * g4.z + b4.z;
    float o3 = (v[3] - mean) * inv * g4.w + b4.w;
    ushortT pk[4] = { f2bf(o0), f2bf(o1), f2bf(o2), f2bf(o3) };
    *(uint2*)(outh + (size_t)row * 256 + d0) = *(uint2*)pk;
    if (outf) {
        float4 of = { o0, o1, o2, o3 };
        *(float4*)(outf + (size_t)row * 256 + d0) = of;
    }
}

// Decoder self-attn over L=8 (batch). qkv bf16 rows n*8+l; out bf16.
__global__ void mha_kernel(const ushortT* __restrict__ qkv, ushortT* __restrict__ o, int nCnt)
{
    int t = blockIdx.x * blockDim.x + threadIdx.x;
    if (t >= nCnt * 64) return;
    int l = t & 7;
    int h = (t >> 3) & 7;
    int n = t >> 6;
    const ushortT* qp = qkv + (size_t)(n * 8 + l) * 768 + h * 32;
    float q[32];
#pragma unroll
    for (int d = 0; d < 32; d++) q[d] = bf2f(qp[d]);
    float sc[8];
#pragma unroll
    for (int s = 0; s < 8; s++) {
        const ushortT* kp = qkv + (size_t)(n * 8 + s) * 768 + 256 + h * 32;
        float acc = 0.f;
#pragma unroll
        for (int d = 0; d < 32; d++) acc = fmaf(q[d], bf2f(kp[d]), acc);
        sc[s] = acc * 0.17677669529663688f;
    }
    float mx = sc[0];
#pragma unroll
    for (int s = 1; s < 8; s++) mx = fmaxf(mx, sc[s]);
    float sum = 0.f;
#pragma unroll
    for (int s = 0; s < 8; s++) { sc[s] = expf(sc[s] - mx); sum += sc[s]; }
    float inv = 1.f / sum;
    float outv[32] = {};
#pragma unroll
    for (int s = 0; s < 8; s++) {
        const ushortT* vp = qkv + (size_t)(n * 8 + s) * 768 + 512 + h * 32;
        float a = sc[s] * inv;
#pragma unroll
        for (int d = 0; d < 32; d++) outv[d] = fmaf(a, bf2f(vp[d]), outv[d]);
    }
    ushortT* op = o + (size_t)(n * 8 + l) * 256 + h * 32;
#pragma unroll
    for (int d = 0; d < 32; d++) op[d] = f2bf(outv[d]);
}

// ---------------------------------------------------------------------------
extern "C" void kernel_launch(void* const* d_in, const int* in_sizes, int n_in,
                              void* d_out, int out_size, void* d_ws, size_t ws_size,
                              hipStream_t stream)
{
    const float* feat0       = (const float*)d_in[0];
    const float* feat1       = (const float*)d_in[1];
    const float* feat2       = (const float*)d_in[2];
    const float* context     = (const float*)d_in[3];
    const float* query_embed = (const float*)d_in[4];
    const float* level_embed = (const float*)d_in[5];
    const float* enc_off_W = (const float*)d_in[6];
    const float* enc_off_b = (const float*)d_in[7];
    const float* enc_aw_W  = (const float*)d_in[8];
    const float* enc_aw_b  = (const float*)d_in[9];
    const float* enc_vp_W  = (const float*)d_in[10];
    const float* enc_vp_b  = (const float*)d_in[11];
    const float* enc_op_W  = (const float*)d_in[12];
    const float* enc_op_b  = (const float*)d_in[13];
    const float* enc_fc1_W = (const float*)d_in[14];
    const float* enc_fc1_b = (const float*)d_in[15];
    const float* enc_fc2_W = (const float*)d_in[16];
    const float* enc_fc2_b = (const float*)d_in[17];
    const float* enc_ln1_g = (const float*)d_in[18];
    const float* enc_ln1_b = (const float*)d_in[19];
    const float* enc_ln2_g = (const float*)d_in[20];
    const float* enc_ln2_b = (const float*)d_in[21];
    const float* dec_off_W = (const float*)d_in[22];
    const float* dec_off_b = (const float*)d_in[23];
    const float* dec_aw_W  = (const float*)d_in[24];
    const float* dec_aw_b  = (const float*)d_in[25];
    const float* dec_vp_W  = (const float*)d_in[26];
    const float* dec_vp_b  = (const float*)d_in[27];
    const float* dec_op_W  = (const float*)d_in[28];
    const float* dec_op_b  = (const float*)d_in[29];
    const float* dec_fc1_W = (const float*)d_in[30];
    const float* dec_fc1_b = (const float*)d_in[31];
    const float* dec_fc2_W = (const float*)d_in[32];
    const float* dec_fc2_b = (const float*)d_in[33];
    const float* dec_ln1_g = (const float*)d_in[34];
    const float* dec_ln1_b = (const float*)d_in[35];
    const float* dec_ln2_g = (const float*)d_in[36];
    const float* dec_ln2_b = (const float*)d_in[37];
    const float* sa_in_W   = (const float*)d_in[38];
    const float* sa_in_b   = (const float*)d_in[39];
    const float* sa_out_W  = (const float*)d_in[40];
    const float* sa_out_b  = (const float*)d_in[41];
    const float* dec_ln3_g = (const float*)d_in[42];
    const float* dec_ln3_b = (const float*)d_in[43];

    const int ME = BSZ * S_TOT;       // 37800
    const int MD = BSZ * NQRY;        // 28800
    const int EW = ME * D_MODEL;      // 9,676,800
    const int DW = MD * D_MODEL;      // 7,372,800

    char* base = (char*)d_ws;
    size_t off = 0;
    auto alloc = [&](size_t bytes) -> char* {
        char* p = base + off;
        off += (bytes + 255) & ~(size_t)255;
        return p;
    };
    ushortT* Xh    = (ushortT*)alloc((size_t)EW * 2);      // encoder state / memory (bf16)
    ushortT* Vh    = (ushortT*)alloc((size_t)EW * 2);      // value projection (bf16)
    ushortT* TGTh  = (ushortT*)alloc((size_t)DW * 2);      // decoder state (bf16)
    float*   POSb  = (float*)alloc((size_t)S_TOT * 256 * 4);
    float*   REFEb = (float*)alloc((size_t)S_TOT * 2 * 4);
    float*   REFDb = (float*)alloc((size_t)NQRY * 2 * 4);
    ushortT* Wbf   = (ushortT*)alloc((size_t)5160960 * 2);
    float*   OBIAS = (float*)alloc((size_t)2 * 3 * 288 * 4);
    ushortT* Yh    = (ushortT*)alloc((size_t)ME * 256 * 2); // GEMM branch output
    char*    R     = alloc((size_t)82252800);               // phase-multiplexed scratch
    if (ws_size < off) return;   // refuse to fault

    // R sub-views (phase-disjoint within each layer phase):
    ushortT* Qh   = (ushortT*)R;                       // [ME,256]  bf16 (enc q)
    float*   OAf  = (float*)(R + 19353600);            // [ME,288]  f32
    ushortT* OUTh = (ushortT*)(R + 62899200);          // [ME,256]  bf16 (msda out)
    ushortT* HIDh = (ushortT*)R;                       // [ME,1024] bf16 (FFN hidden)
    ushortT* QKVh = (ushortT*)R;                       // [MD,768]  bf16 (self-attn)
    ushortT* SOh  = (ushortT*)(R + 44236800);          // [MD,256]  bf16 (attn out)

    size_t wo = 0;
    auto walloc = [&](size_t elems) -> ushortT* { ushortT* p = Wbf + wo; wo += elems; return p; };
    ushortT* h_enc_offaw = walloc(3 * 288 * 256);
    ushortT* h_enc_vp    = walloc(3 * 65536);
    ushortT* h_enc_op    = walloc(3 * 65536);
    ushortT* h_enc_fc1   = walloc(3 * 262144);
    ushortT* h_enc_fc2   = walloc(3 * 262144);
    ushortT* h_dec_offaw = walloc(3 * 288 * 256);
    ushortT* h_dec_vp    = walloc(3 * 65536);
    ushortT* h_dec_op    = walloc(3 * 65536);
    ushortT* h_dec_fc1   = walloc(3 * 262144);
    ushortT* h_dec_fc2   = walloc(3 * 262144);
    ushortT* h_sa_in     = walloc(3 * 196608);
    ushortT* h_sa_out    = walloc(3 * 65536);
    float* enc_oab = OBIAS;
    float* dec_oab = OBIAS + 3 * 288;

    auto conv = [&](const float* s, ushortT* d, int n) {
        hipLaunchKernelGGL(f2bf_kernel, dim3((n + 255) / 256), dim3(256), 0, stream, s, d, n);
    };
    hipLaunchKernelGGL(conv_offaw_kernel, dim3((3 * 288 * 256 + 255) / 256), dim3(256), 0, stream,
                       enc_off_W, enc_aw_W, h_enc_offaw);
    hipLaunchKernelGGL(conv_offaw_kernel, dim3((3 * 288 * 256 + 255) / 256), dim3(256), 0, stream,
                       dec_off_W, dec_aw_W, h_dec_offaw);
    hipLaunchKernelGGL(conv_offaw_bias_kernel, dim3(4), dim3(256), 0, stream,
                       enc_off_b, enc_aw_b, enc_oab);
    hipLaunchKernelGGL(conv_offaw_bias_kernel, dim3(4), dim3(256), 0, stream,
                       dec_off_b, dec_aw_b, dec_oab);
    conv(enc_vp_W,  h_enc_vp,  3 * 65536);
    conv(enc_op_W,  h_enc_op,  3 * 65536);
    conv(enc_fc1_W, h_enc_fc1, 3 * 262144);
    conv(enc_fc2_W, h_enc_fc2, 3 * 262144);
    conv(dec_vp_W,  h_dec_vp,  3 * 65536);
    conv(dec_op_W,  h_dec_op,  3 * 65536);
    conv(dec_fc1_W, h_dec_fc1, 3 * 262144);
    conv(dec_fc2_W, h_dec_fc2, 3 * 262144);
    conv(sa_in_W,   h_sa_in,   3 * 196608);
    conv(sa_out_W,  h_sa_out,  3 * 65536);

    // ---- setup ----
    hipLaunchKernelGGL(build_pos_kernel, dim3((S_TOT * 256 + 255) / 256), dim3(256), 0, stream,
                       level_embed, POSb);
    hipLaunchKernelGGL(build_ref_kernel, dim3((S_TOT + NQRY + 255) / 256), dim3(256), 0, stream,
                       REFEb, REFDb);
    hipLaunchKernelGGL(transpose_feat_kernel, dim3(113, 8, 8), dim3(256), 0, stream,
                       feat0, Xh, 3600, 0);
    hipLaunchKernelGGL(transpose_feat_kernel, dim3(29, 8, 8), dim3(256), 0, stream,
                       feat1, Xh, 900, 3600);
    hipLaunchKernelGGL(transpose_feat_kernel, dim3(8, 8, 8), dim3(256), 0, stream,
                       feat2, Xh, 225, 4500);
    hipLaunchKernelGGL(build_tgt_kernel, dim3((MD * 64 + 255) / 256), dim3(256), 0, stream,
                       context, query_embed, TGTh);

    // ---- encoder ----
    for (int i = 0; i < 3; i++) {
        gemm_bf16(Xh, h_enc_vp + (size_t)i * 65536, enc_vp_b + i * 256, Vh, ME, 256, 256, 0, 1, stream);
        hipLaunchKernelGGL(add_pos_kernel, dim3((ME * 64 + 255) / 256), dim3(256), 0, stream,
                           Xh, POSb, Qh);
        gemm_bf16(Qh, h_enc_offaw + (size_t)i * 73728, enc_oab + i * 288, OAf, ME, 288, 256, 0, 0, stream);
        hipLaunchKernelGGL(msda_kernel, dim3((ME + MROWS - 1) / MROWS), dim3(256), 0, stream,
                           Vh, OAf, REFEb, OUTh, 0, ME);
        gemm_bf16(OUTh, h_enc_op + (size_t)i * 65536, enc_op_b + i * 256, Yh, ME, 256, 256, 0, 1, stream);
        hipLaunchKernelGGL(ln_res_kernel, dim3((ME + 3) / 4), dim3(256), 0, stream,
                           Xh, Yh, enc_ln1_g + i * 256, enc_ln1_b + i * 256, Xh, (float*)nullptr, ME);
        gemm_bf16(Xh, h_enc_fc1 + (size_t)i * 262144, enc_fc1_b + i * 1024, HIDh, ME, 1024, 256, 1, 1, stream);
        gemm_bf16(HIDh, h_enc_fc2 + (size_t)i * 262144, enc_fc2_b + i * 256, Yh, ME, 256, 1024, 0, 1, stream);
        hipLaunchKernelGGL(ln_res_kernel, dim3((ME + 3) / 4), dim3(256), 0, stream,
                           Xh, Yh, enc_ln2_g + i * 256, enc_ln2_b + i * 256, Xh, (float*)nullptr, ME);
    }
    // Xh now holds `memory`.

    // ---- decoder (state in [NQ,BS,D] row order throughout) ----
    for (int i = 0; i < 3; i++) {
        gemm_bf16(TGTh, h_sa_in + (size_t)i * 196608, sa_in_b + i * 768, QKVh, MD, 768, 256, 0, 1, stream);
        hipLaunchKernelGGL(mha_kernel, dim3((MD * 8 + 255) / 256), dim3(256), 0, stream,
                           QKVh, SOh, MD / 8);
        gemm_bf16(SOh, h_sa_out + (size_t)i * 65536, sa_out_b + i * 256, Yh, MD, 256, 256, 0, 1, stream);
        hipLaunchKernelGGL(ln_res_kernel, dim3((MD + 3) / 4), dim3(256), 0, stream,
                           TGTh, Yh, dec_ln2_g + i * 256, dec_ln2_b + i * 256, TGTh, (float*)nullptr, MD);
        gemm_bf16(Xh, h_dec_vp + (size_t)i * 65536, dec_vp_b + i * 256, Vh, ME, 256, 256, 0, 1, stream);
        gemm_bf16(TGTh, h_dec_offaw + (size_t)i * 73728, dec_oab + i * 288, OAf, MD, 288, 256, 0, 0, stream);
        hipLaunchKernelGGL(msda_kernel, dim3((MD + MROWS - 1) / MROWS), dim3(256), 0, stream,
                           Vh, OAf, REFDb, OUTh, 1, MD);
        gemm_bf16(OUTh, h_dec_op + (size_t)i * 65536, dec_op_b + i * 256, Yh, MD, 256, 256, 0, 1, stream);
        hipLaunchKernelGGL(ln_res_kernel, dim3((MD + 3) / 4), dim3(256), 0, stream,
                           TGTh, Yh, dec_ln1_g + i * 256, dec_ln1_b + i * 256, TGTh, (float*)nullptr, MD);
        gemm_bf16(TGTh, h_dec_fc1 + (size_t)i * 262144, dec_fc1_b + i * 1024, HIDh, MD, 1024, 256, 1, 1, stream);
        gemm_bf16(HIDh, h_dec_fc2 + (size_t)i * 262144, dec_fc2_b + i * 256, Yh, MD, 256, 1024, 0, 1, stream);
        float* outf = (i == 2) ? (float*)d_out : nullptr;
        hipLaunchKernelGGL(ln_res_kernel, dim3((MD + 3) / 4), dim3(256), 0, stream,
                           TGTh, Yh, dec_ln3_g + i * 256, dec_ln3_b + i * 256, TGTh, outf, MD);
    }
}

// Round 7
// 1728.536 us; speedup vs baseline: 8.3997x; 1.1728x over previous
//
#include <hip/hip_runtime.h>
#include <cmath>

#define D_MODEL 256
#define NHEADS 8
#define BSZ 8
#define S_TOT 4725
#define NQRY 3600

typedef unsigned short ushortT;
using bf16x8  = __attribute__((ext_vector_type(8))) __bf16;
using floatx4 = __attribute__((ext_vector_type(4))) float;

__device__ __forceinline__ ushortT f2bf(float f)
{
    union { float f; unsigned u; } v; v.f = f;
    unsigned r = v.u + 0x7FFFu + ((v.u >> 16) & 1u);
    return (ushortT)(r >> 16);
}
__device__ __forceinline__ float bf2f(ushortT u)
{
    union { unsigned u; float f; } v; v.u = ((unsigned)u) << 16;
    return v.f;
}
__device__ __forceinline__ float bits2f(unsigned u)
{
    union { unsigned u; float f; } v; v.u = u;
    return v.f;
}

#define GLD16(gp, lp) __builtin_amdgcn_global_load_lds( \
    (const __attribute__((address_space(1))) void*)(gp), \
    (__attribute__((address_space(3))) void*)(lp), 16, 0, 0)

// ---------------------------------------------------------------------------
// bf16 MFMA GEMM with async global->LDS staging.
// XOR-swizzled LDS chunks (bank-conflict-free fragment reads) +
// LDS-staged coalesced bf16 epilogue (16B stores, full cache lines).
// ---------------------------------------------------------------------------
template<int RELU, int OUTBF>
__global__ __launch_bounds__(256) void gemm_bf16_kernel(
    const ushortT* __restrict__ A, const ushortT* __restrict__ W,
    const float* __restrict__ bias, void* __restrict__ Cout,
    int M, int N, int K)
{
    __shared__ ushortT SM[128 * 32 * 2];
    ushortT* As = SM;
    ushortT* Bs = SM + 128 * 32;
    const int tid  = threadIdx.x;
    const int lane = tid & 63;
    const int wid  = tid >> 6;
    const int bm = blockIdx.x * 128;
    const int bn = blockIdx.y * 128;
    const int wm = (wid & 1) * 64;
    const int wn = (wid >> 1) * 64;
    const int col16 = lane & 15;
    const int quad  = lane >> 4;
    const int srow = lane >> 2;
    // staging source-chunk permutation: LDS[row][c'] = global[row][c' ^ ((row>>1)&3)]
    const int cperm = (lane & 3) ^ ((lane >> 3) & 3);
    // fragment-read chunk permutation (row parity-derived, = ((col16>>1)&3))
    const int rxor = (col16 >> 1) & 3;

    floatx4 acc[4][4];
#pragma unroll
    for (int i = 0; i < 4; i++)
#pragma unroll
        for (int j = 0; j < 4; j++) acc[i][j] = (floatx4){0.f, 0.f, 0.f, 0.f};

    const int rbase = wid * 32;
    for (int k0 = 0; k0 < K; k0 += 32) {
        if (k0) __syncthreads();
#pragma unroll
        for (int j = 0; j < 2; j++) {
            int row = rbase + j * 16 + srow;
            int gm = bm + row; if (gm >= M) gm = M - 1;
            GLD16(A + (size_t)gm * K + k0 + cperm * 8, &As[(rbase + j * 16) * 32]);
            int gn = bn + row; if (gn >= N) gn = N - 1;
            GLD16(W + (size_t)gn * K + k0 + cperm * 8, &Bs[(rbase + j * 16) * 32]);
        }
        __syncthreads();
        bf16x8 av[4], bv[4];
#pragma unroll
        for (int i = 0; i < 4; i++) {
            av[i] = *(const bf16x8*)&As[(wm + i * 16 + col16) * 32 + (quad ^ rxor) * 8];
            bv[i] = *(const bf16x8*)&Bs[(wn + i * 16 + col16) * 32 + (quad ^ rxor) * 8];
        }
#pragma unroll
        for (int mi = 0; mi < 4; mi++)
#pragma unroll
            for (int ni = 0; ni < 4; ni++)
                acc[mi][ni] = __builtin_amdgcn_mfma_f32_16x16x32_bf16(
                    av[mi], bv[ni], acc[mi][ni], 0, 0, 0);
    }

    if (OUTBF) {
        // LDS-staged epilogue: per-wave 16x64 chunk, stride 72 (144B rows, 16B aligned)
        __syncthreads();
        ushortT* cs = SM + wid * (16 * 72);
        const int row_l = lane >> 2;
        const int colg  = (lane & 3) * 16;
#pragma unroll
        for (int mi = 0; mi < 4; mi++) {
#pragma unroll
            for (int ni = 0; ni < 4; ni++) {
                int gn = bn + wn + ni * 16 + col16;
                float bs = bias[gn < N ? gn : N - 1];
#pragma unroll
                for (int r = 0; r < 4; r++) {
                    float v = acc[mi][ni][r] + bs;
                    if (RELU) v = fmaxf(v, 0.f);
                    cs[(quad * 4 + r) * 72 + ni * 16 + col16] = f2bf(v);
                }
            }
            int gm = bm + wm + mi * 16 + row_l;
            int gn0 = bn + wn + colg;
            if (gm < M) {
                ushortT* dst = (ushortT*)Cout + (size_t)gm * N + gn0;
                if (gn0 + 8 <= N)  *(uint4*)dst       = *(uint4*)&cs[row_l * 72 + colg];
                if (gn0 + 16 <= N) *(uint4*)(dst + 8) = *(uint4*)&cs[row_l * 72 + colg + 8];
            }
        }
    } else {
        // fp32 path: scalar stores already cover full 64B lines per quad
#pragma unroll
        for (int ni = 0; ni < 4; ni++) {
            int gn = bn + wn + ni * 16 + col16;
            if (gn >= N) continue;
            float bs = bias[gn];
#pragma unroll
            for (int mi = 0; mi < 4; mi++) {
#pragma unroll
                for (int r = 0; r < 4; r++) {
                    int gm = bm + wm + mi * 16 + quad * 4 + r;
                    if (gm >= M) continue;
                    float v = acc[mi][ni][r] + bs;
                    if (RELU) v = fmaxf(v, 0.f);
                    ((float*)Cout)[(size_t)gm * N + gn] = v;
                }
            }
        }
    }
}

static inline void gemm_bf16(const ushortT* A, const ushortT* W, const float* bias,
                             void* C, int M, int N, int K, int relu, int outbf,
                             hipStream_t s)
{
    dim3 g((M + 127) / 128, (N + 127) / 128);
    if (relu) {
        if (outbf) hipLaunchKernelGGL((gemm_bf16_kernel<1,1>), g, dim3(256), 0, s, A, W, bias, C, M, N, K);
        else       hipLaunchKernelGGL((gemm_bf16_kernel<1,0>), g, dim3(256), 0, s, A, W, bias, C, M, N, K);
    } else {
        if (outbf) hipLaunchKernelGGL((gemm_bf16_kernel<0,1>), g, dim3(256), 0, s, A, W, bias, C, M, N, K);
        else       hipLaunchKernelGGL((gemm_bf16_kernel<0,0>), g, dim3(256), 0, s, A, W, bias, C, M, N, K);
    }
}

// ---------------------------------------------------------------------------
__global__ void f2bf_kernel(const float* __restrict__ src, ushortT* __restrict__ dst, int n)
{
    int t = blockIdx.x * blockDim.x + threadIdx.x;
    if (t < n) dst[t] = f2bf(src[t]);
}

__global__ void conv_offaw_kernel(const float* __restrict__ offW, const float* __restrict__ awW,
                                  ushortT* __restrict__ dst)
{
    int t = blockIdx.x * blockDim.x + threadIdx.x;
    if (t >= 3 * 288 * 256) return;
    int c = t & 255;
    int r = (t >> 8) % 288;
    int i = t / (288 * 256);
    float v = (r < 192) ? offW[((size_t)i * 192 + r) * 256 + c]
                        : awW[((size_t)i * 96 + (r - 192)) * 256 + c];
    dst[t] = f2bf(v);
}

__global__ void conv_offaw_bias_kernel(const float* __restrict__ offb, const float* __restrict__ awb,
                                       float* __restrict__ dst)
{
    int t = blockIdx.x * blockDim.x + threadIdx.x;
    if (t >= 3 * 288) return;
    int r = t % 288;
    int i = t / 288;
    dst[t] = (r < 192) ? offb[i * 192 + r] : awb[i * 96 + (r - 192)];
}

__device__ __forceinline__ void level_of(int s, int& l, int& H, int& W, int& hw)
{
    if (s < 3600)      { l = 0; H = 60; W = 60; hw = s; }
    else if (s < 4500) { l = 1; H = 30; W = 30; hw = s - 3600; }
    else               { l = 2; H = 15; W = 15; hw = s - 4500; }
}

// LDS-tiled transpose: f[b][d0+.][hw] (fp32) -> Xh[b][s0+hw][d0+.] (bf16)
__global__ __launch_bounds__(256) void transpose_feat_kernel(
    const float* __restrict__ f, ushortT* __restrict__ Xh, int HW, int s0)
{
    __shared__ float tile[32][33];
    const int b  = blockIdx.z;
    const int hw0 = blockIdx.x * 32;
    const int d0  = blockIdx.y * 32;
    const int tx = threadIdx.x & 31;
    const int ty = threadIdx.x >> 5;
    const float* fb = f + ((size_t)b * 256 + d0) * HW + hw0;
#pragma unroll
    for (int r = ty; r < 32; r += 8) {
        if (hw0 + tx < HW) tile[r][tx] = fb[(size_t)r * HW + tx];
    }
    __syncthreads();
    ushortT* xb = Xh + ((size_t)b * S_TOT + s0 + hw0) * 256 + d0;
#pragma unroll
    for (int r = ty; r < 32; r += 8) {
        if (hw0 + r < HW) xb[(size_t)r * 256 + tx] = f2bf(tile[tx][r]);
    }
}

__global__ void build_pos_kernel(const float* __restrict__ level_embed, float* __restrict__ pos)
{
    int t = blockIdx.x * blockDim.x + threadIdx.x;
    if (t >= S_TOT * D_MODEL) return;
    int d = t & 255;
    int s = t >> 8;
    int l, H, W, hw; level_of(s, l, H, W, hw);
    int y = hw / W, x = hw % W;
    int dd = (d < 128) ? d : d - 128;
    float v = (d < 128)
        ? ((float)(y + 1)) / ((float)H + 1e-6f) * 6.28318530717958647692f
        : ((float)(x + 1)) / ((float)W + 1e-6f) * 6.28318530717958647692f;
    float tpow = powf(10000.f, (float)(2 * (dd >> 1)) * (1.f / 128.f));
    float arg = v / tpow;
    float val = (dd & 1) ? cosf(arg) : sinf(arg);
    pos[t] = val + level_embed[l * D_MODEL + d];
}

__global__ void build_ref_kernel(float* __restrict__ refE, float* __restrict__ refD)
{
    int t = blockIdx.x * blockDim.x + threadIdx.x;
    if (t < S_TOT) {
        int l, H, W, hw; level_of(t, l, H, W, hw);
        int y = hw / W, x = hw % W;
        refE[2 * t]     = ((float)x + 0.5f) / (float)W;
        refE[2 * t + 1] = ((float)y + 0.5f) / (float)H;
    } else if (t < S_TOT + NQRY) {
        int q = t - S_TOT;
        int y = q / 60, x = q % 60;
        refD[2 * q]     = ((float)x + 0.5f) / 60.f;
        refD[2 * q + 1] = ((float)y + 0.5f) / 60.f;
    }
}

__global__ void build_tgt_kernel(const float* __restrict__ context, const float* __restrict__ qe,
                                 ushortT* __restrict__ TGTh)
{
    int t = blockIdx.x * blockDim.x + threadIdx.x;
    if (t >= NQRY * BSZ * 64) return;
    int gi = t & 63;
    int row = t >> 6;
    int nq = row >> 3;
    int d0 = gi * 4;
    const float4 c4 = *(const float4*)(context + (size_t)row * 256 + d0);
    const float4 q4 = *(const float4*)(qe + (size_t)nq * 256 + d0);
    ushortT pk[4] = { f2bf(c4.x + q4.x), f2bf(c4.y + q4.y), f2bf(c4.z + q4.z), f2bf(c4.w + q4.w) };
    *(uint2*)(TGTh + (size_t)row * 256 + d0) = *(uint2*)pk;
}

__global__ void add_pos_kernel(const ushortT* __restrict__ Xh, const float* __restrict__ pos,
                               ushortT* __restrict__ Qh)
{
    int t = blockIdx.x * blockDim.x + threadIdx.x;
    if (t >= BSZ * S_TOT * 64) return;
    int gi = t & 63;
    int row = t >> 6;
    int s = row % S_TOT;
    int d0 = gi * 4;
    ushortT x4[4];
    *(uint2*)x4 = *(const uint2*)(Xh + (size_t)row * 256 + d0);
    const float4 p4 = *(const float4*)(pos + (size_t)s * 256 + d0);
    ushortT pk[4] = { f2bf(bf2f(x4[0]) + p4.x), f2bf(bf2f(x4[1]) + p4.y),
                      f2bf(bf2f(x4[2]) + p4.z), f2bf(bf2f(x4[3]) + p4.w) };
    *(uint2*)(Qh + (size_t)row * 256 + d0) = *(uint2*)pk;
}

// ---------------------------------------------------------------------------
// MSDA sampling: block = 8 rows; thread = (row, head, chgroup of 8).
// ---------------------------------------------------------------------------
#define MROWS 8
__global__ __launch_bounds__(256) void msda_kernel(
    const ushortT* __restrict__ value, const float* __restrict__ oa,
    const float* __restrict__ ref, ushortT* __restrict__ out,
    int mode, int total_rows)
{
    __shared__ float sOff[MROWS][192];
    __shared__ float sW[MROWS][96];
    const int br0 = blockIdx.x * MROWS;

    for (int idx = threadIdx.x; idx < MROWS * 288; idx += 256) {
        int r = idx / 288, c = idx - r * 288;
        int lm = br0 + r;
        float v = (lm < total_rows) ? oa[(size_t)lm * 288 + c] : 0.f;
        if (c < 192) sOff[r][c] = v;
        else         sW[r][c - 192] = v;
    }
    __syncthreads();
    if (threadIdx.x < 64) {
        int r = threadIdx.x >> 3, h = threadIdx.x & 7;
        float* p = &sW[r][h * 12];
        float mx = p[0];
#pragma unroll
        for (int i = 1; i < 12; i++) mx = fmaxf(mx, p[i]);
        float ssum = 0.f;
        float e[12];
#pragma unroll
        for (int i = 0; i < 12; i++) { e[i] = expf(p[i] - mx); ssum += e[i]; }
        float inv = 1.f / ssum;
#pragma unroll
        for (int i = 0; i < 12; i++) p[i] = e[i] * inv;
    }
    __syncthreads();

    const int r  = threadIdx.x >> 5;
    const int h  = (threadIdx.x >> 2) & 7;
    const int cg = threadIdx.x & 3;
    const int lm = br0 + r;
    if (lm >= total_rows) return;
    int b, q;
    if (mode == 0) { b = lm / S_TOT; q = lm - b * S_TOT; }
    else           { q = lm >> 3;    b = lm & 7; }
    const float rx = ref[2 * q], ry = ref[2 * q + 1];
    const float* offp = &sOff[r][h * 24];
    const float* wp   = &sW[r][h * 12];

    float acc[8] = {};
    const int HWs[3][3] = {{60, 60, 0}, {30, 30, 3600}, {15, 15, 4500}};
#pragma unroll
    for (int l = 0; l < 3; l++) {
        const int H = HWs[l][0], W = HWs[l][1], s0 = HWs[l][2];
        const ushortT* vbase = value + ((size_t)b * S_TOT + s0) * 256 + h * 32 + cg * 8;
#pragma unroll
        for (int p = 0; p < 4; p++) {
            float ox = offp[(l * 4 + p) * 2];
            float oy = offp[(l * 4 + p) * 2 + 1];
            float w  = wp[l * 4 + p];
            float lx = rx * W + ox - 0.5f;
            float ly = ry * H + oy - 0.5f;
            float x0f = floorf(lx), y0f = floorf(ly);
            int x0 = (int)x0f, y0 = (int)y0f;
            float wx1 = lx - x0f, wy1 = ly - y0f;
            float wx0 = 1.f - wx1, wy0 = 1.f - wy1;
#pragma unroll
            for (int dy = 0; dy < 2; dy++)
#pragma unroll
                for (int dx = 0; dx < 2; dx++) {
                    int xi = x0 + dx, yi = y0 + dy;
                    if (xi >= 0 && xi < W && yi >= 0 && yi < H) {
                        float cw = w * (dx ? wx1 : wx0) * (dy ? wy1 : wy0);
                        uint4 v4 = *(const uint4*)(vbase + (size_t)(yi * W + xi) * 256);
                        acc[0] = fmaf(cw, bits2f(v4.x << 16), acc[0]);
                        acc[1] = fmaf(cw, bits2f(v4.x & 0xFFFF0000u), acc[1]);
                        acc[2] = fmaf(cw, bits2f(v4.y << 16), acc[2]);
                        acc[3] = fmaf(cw, bits2f(v4.y & 0xFFFF0000u), acc[3]);
                        acc[4] = fmaf(cw, bits2f(v4.z << 16), acc[4]);
                        acc[5] = fmaf(cw, bits2f(v4.z & 0xFFFF0000u), acc[5]);
                        acc[6] = fmaf(cw, bits2f(v4.w << 16), acc[6]);
                        acc[7] = fmaf(cw, bits2f(v4.w & 0xFFFF0000u), acc[7]);
                    }
                }
        }
    }
    ushortT pk[8];
#pragma unroll
    for (int i = 0; i < 8; i++) pk[i] = f2bf(acc[i]);
    *(uint4*)(out + (size_t)lm * 256 + h * 32 + cg * 8) = *(uint4*)pk;
}

// ---------------------------------------------------------------------------
// LN over bf16 residual stream
// ---------------------------------------------------------------------------
__global__ void ln_res_kernel(const ushortT* __restrict__ x, const ushortT* __restrict__ a,
                              const float* __restrict__ g, const float* __restrict__ b,
                              ushortT* __restrict__ outh, float* __restrict__ outf, int M)
{
    int wave = threadIdx.x >> 6;
    int lane = threadIdx.x & 63;
    int row = blockIdx.x * 4 + wave;
    if (row >= M) return;
    const int d0 = lane * 4;
    ushortT x4[4], a4[4];
    *(uint2*)x4 = *(const uint2*)(x + (size_t)row * 256 + d0);
    *(uint2*)a4 = *(const uint2*)(a + (size_t)row * 256 + d0);
    float v[4];
    float s = 0.f;
#pragma unroll
    for (int i = 0; i < 4; i++) { v[i] = bf2f(x4[i]) + bf2f(a4[i]); s += v[i]; }
#pragma unroll
    for (int o = 32; o > 0; o >>= 1) s += __shfl_down(s, o);
    s = __shfl(s, 0);
    float mean = s * (1.f / 256.f);
    float vs = 0.f;
#pragma unroll
    for (int i = 0; i < 4; i++) { float d = v[i] - mean; vs += d * d; }
#pragma unroll
    for (int o = 32; o > 0; o >>= 1) vs += __shfl_down(vs, o);
    vs = __shfl(vs, 0);
    float inv = rsqrtf(vs * (1.f / 256.f) + 1e-5f);
    const float4 g4 = *(const float4*)(g + d0);
    const float4 b4 = *(const float4*)(b + d0);
    float o0 = (v[0] - mean) * inv * g4.x + b4.x;
    float o1 = (v[1] - mean) * inv * g4.y + b4.y;
    float o2 = (v[2] - mean) * inv * g4.z + b4.z;
    float o3 = (v[3] - mean) * inv * g4.w + b4.w;
    ushortT pk[4] = { f2bf(o0), f2bf(o1), f2bf(o2), f2bf(o3) };
    *(uint2*)(outh + (size_t)row * 256 + d0) = *(uint2*)pk;
    if (outf) {
        float4 of = { o0, o1, o2, o3 };
        *(float4*)(outf + (size_t)row * 256 + d0) = of;
    }
}

// Decoder self-attn over L=8 (batch). qkv bf16 rows n*8+l; out bf16.
__global__ void mha_kernel(const ushortT* __restrict__ qkv, ushortT* __restrict__ o, int nCnt)
{
    int t = blockIdx.x * blockDim.x + threadIdx.x;
    if (t >= nCnt * 64) return;
    int l = t & 7;
    int h = (t >> 3) & 7;
    int n = t >> 6;
    const ushortT* qp = qkv + (size_t)(n * 8 + l) * 768 + h * 32;
    float q[32];
#pragma unroll
    for (int d = 0; d < 32; d++) q[d] = bf2f(qp[d]);
    float sc[8];
#pragma unroll
    for (int s = 0; s < 8; s++) {
        const ushortT* kp = qkv + (size_t)(n * 8 + s) * 768 + 256 + h * 32;
        float acc = 0.f;
#pragma unroll
        for (int d = 0; d < 32; d++) acc = fmaf(q[d], bf2f(kp[d]), acc);
        sc[s] = acc * 0.17677669529663688f;
    }
    float mx = sc[0];
#pragma unroll
    for (int s = 1; s < 8; s++) mx = fmaxf(mx, sc[s]);
    float sum = 0.f;
#pragma unroll
    for (int s = 0; s < 8; s++) { sc[s] = expf(sc[s] - mx); sum += sc[s]; }
    float inv = 1.f / sum;
    float outv[32] = {};
#pragma unroll
    for (int s = 0; s < 8; s++) {
        const ushortT* vp = qkv + (size_t)(n * 8 + s) * 768 + 512 + h * 32;
        float a = sc[s] * inv;
#pragma unroll
        for (int d = 0; d < 32; d++) outv[d] = fmaf(a, bf2f(vp[d]), outv[d]);
    }
    ushortT* op = o + (size_t)(n * 8 + l) * 256 + h * 32;
#pragma unroll
    for (int d = 0; d < 32; d++) op[d] = f2bf(outv[d]);
}

// ---------------------------------------------------------------------------
extern "C" void kernel_launch(void* const* d_in, const int* in_sizes, int n_in,
                              void* d_out, int out_size, void* d_ws, size_t ws_size,
                              hipStream_t stream)
{
    const float* feat0       = (const float*)d_in[0];
    const float* feat1       = (const float*)d_in[1];
    const float* feat2       = (const float*)d_in[2];
    const float* context     = (const float*)d_in[3];
    const float* query_embed = (const float*)d_in[4];
    const float* level_embed = (const float*)d_in[5];
    const float* enc_off_W = (const float*)d_in[6];
    const float* enc_off_b = (const float*)d_in[7];
    const float* enc_aw_W  = (const float*)d_in[8];
    const float* enc_aw_b  = (const float*)d_in[9];
    const float* enc_vp_W  = (const float*)d_in[10];
    const float* enc_vp_b  = (const float*)d_in[11];
    const float* enc_op_W  = (const float*)d_in[12];
    const float* enc_op_b  = (const float*)d_in[13];
    const float* enc_fc1_W = (const float*)d_in[14];
    const float* enc_fc1_b = (const float*)d_in[15];
    const float* enc_fc2_W = (const float*)d_in[16];
    const float* enc_fc2_b = (const float*)d_in[17];
    const float* enc_ln1_g = (const float*)d_in[18];
    const float* enc_ln1_b = (const float*)d_in[19];
    const float* enc_ln2_g = (const float*)d_in[20];
    const float* enc_ln2_b = (const float*)d_in[21];
    const float* dec_off_W = (const float*)d_in[22];
    const float* dec_off_b = (const float*)d_in[23];
    const float* dec_aw_W  = (const float*)d_in[24];
    const float* dec_aw_b  = (const float*)d_in[25];
    const float* dec_vp_W  = (const float*)d_in[26];
    const float* dec_vp_b  = (const float*)d_in[27];
    const float* dec_op_W  = (const float*)d_in[28];
    const float* dec_op_b  = (const float*)d_in[29];
    const float* dec_fc1_W = (const float*)d_in[30];
    const float* dec_fc1_b = (const float*)d_in[31];
    const float* dec_fc2_W = (const float*)d_in[32];
    const float* dec_fc2_b = (const float*)d_in[33];
    const float* dec_ln1_g = (const float*)d_in[34];
    const float* dec_ln1_b = (const float*)d_in[35];
    const float* dec_ln2_g = (const float*)d_in[36];
    const float* dec_ln2_b = (const float*)d_in[37];
    const float* sa_in_W   = (const float*)d_in[38];
    const float* sa_in_b   = (const float*)d_in[39];
    const float* sa_out_W  = (const float*)d_in[40];
    const float* sa_out_b  = (const float*)d_in[41];
    const float* dec_ln3_g = (const float*)d_in[42];
    const float* dec_ln3_b = (const float*)d_in[43];

    const int ME = BSZ * S_TOT;       // 37800
    const int MD = BSZ * NQRY;        // 28800
    const int EW = ME * D_MODEL;
    const int DW = MD * D_MODEL;

    char* base = (char*)d_ws;
    size_t off = 0;
    auto alloc = [&](size_t bytes) -> char* {
        char* p = base + off;
        off += (bytes + 255) & ~(size_t)255;
        return p;
    };
    ushortT* Xh    = (ushortT*)alloc((size_t)EW * 2);
    ushortT* Vh    = (ushortT*)alloc((size_t)EW * 2);
    ushortT* TGTh  = (ushortT*)alloc((size_t)DW * 2);
    float*   POSb  = (float*)alloc((size_t)S_TOT * 256 * 4);
    float*   REFEb = (float*)alloc((size_t)S_TOT * 2 * 4);
    float*   REFDb = (float*)alloc((size_t)NQRY * 2 * 4);
    ushortT* Wbf   = (ushortT*)alloc((size_t)5160960 * 2);
    float*   OBIAS = (float*)alloc((size_t)2 * 3 * 288 * 4);
    ushortT* Yh    = (ushortT*)alloc((size_t)ME * 256 * 2);
    char*    R     = alloc((size_t)82252800);
    if (ws_size < off) return;

    ushortT* Qh   = (ushortT*)R;
    float*   OAf  = (float*)(R + 19353600);
    ushortT* OUTh = (ushortT*)(R + 62899200);
    ushortT* HIDh = (ushortT*)R;
    ushortT* QKVh = (ushortT*)R;
    ushortT* SOh  = (ushortT*)(R + 44236800);

    size_t wo = 0;
    auto walloc = [&](size_t elems) -> ushortT* { ushortT* p = Wbf + wo; wo += elems; return p; };
    ushortT* h_enc_offaw = walloc(3 * 288 * 256);
    ushortT* h_enc_vp    = walloc(3 * 65536);
    ushortT* h_enc_op    = walloc(3 * 65536);
    ushortT* h_enc_fc1   = walloc(3 * 262144);
    ushortT* h_enc_fc2   = walloc(3 * 262144);
    ushortT* h_dec_offaw = walloc(3 * 288 * 256);
    ushortT* h_dec_vp    = walloc(3 * 65536);
    ushortT* h_dec_op    = walloc(3 * 65536);
    ushortT* h_dec_fc1   = walloc(3 * 262144);
    ushortT* h_dec_fc2   = walloc(3 * 262144);
    ushortT* h_sa_in     = walloc(3 * 196608);
    ushortT* h_sa_out    = walloc(3 * 65536);
    float* enc_oab = OBIAS;
    float* dec_oab = OBIAS + 3 * 288;

    auto conv = [&](const float* s, ushortT* d, int n) {
        hipLaunchKernelGGL(f2bf_kernel, dim3((n + 255) / 256), dim3(256), 0, stream, s, d, n);
    };
    hipLaunchKernelGGL(conv_offaw_kernel, dim3((3 * 288 * 256 + 255) / 256), dim3(256), 0, stream,
                       enc_off_W, enc_aw_W, h_enc_offaw);
    hipLaunchKernelGGL(conv_offaw_kernel, dim3((3 * 288 * 256 + 255) / 256), dim3(256), 0, stream,
                       dec_off_W, dec_aw_W, h_dec_offaw);
    hipLaunchKernelGGL(conv_offaw_bias_kernel, dim3(4), dim3(256), 0, stream,
                       enc_off_b, enc_aw_b, enc_oab);
    hipLaunchKernelGGL(conv_offaw_bias_kernel, dim3(4), dim3(256), 0, stream,
                       dec_off_b, dec_aw_b, dec_oab);
    conv(enc_vp_W,  h_enc_vp,  3 * 65536);
    conv(enc_op_W,  h_enc_op,  3 * 65536);
    conv(enc_fc1_W, h_enc_fc1, 3 * 262144);
    conv(enc_fc2_W, h_enc_fc2, 3 * 262144);
    conv(dec_vp_W,  h_dec_vp,  3 * 65536);
    conv(dec_op_W,  h_dec_op,  3 * 65536);
    conv(dec_fc1_W, h_dec_fc1, 3 * 262144);
    conv(dec_fc2_W, h_dec_fc2, 3 * 262144);
    conv(sa_in_W,   h_sa_in,   3 * 196608);
    conv(sa_out_W,  h_sa_out,  3 * 65536);

    // ---- setup ----
    hipLaunchKernelGGL(build_pos_kernel, dim3((S_TOT * 256 + 255) / 256), dim3(256), 0, stream,
                       level_embed, POSb);
    hipLaunchKernelGGL(build_ref_kernel, dim3((S_TOT + NQRY + 255) / 256), dim3(256), 0, stream,
                       REFEb, REFDb);
    hipLaunchKernelGGL(transpose_feat_kernel, dim3(113, 8, 8), dim3(256), 0, stream,
                       feat0, Xh, 3600, 0);
    hipLaunchKernelGGL(transpose_feat_kernel, dim3(29, 8, 8), dim3(256), 0, stream,
                       feat1, Xh, 900, 3600);
    hipLaunchKernelGGL(transpose_feat_kernel, dim3(8, 8, 8), dim3(256), 0, stream,
                       feat2, Xh, 225, 4500);
    hipLaunchKernelGGL(build_tgt_kernel, dim3((MD * 64 + 255) / 256), dim3(256), 0, stream,
                       context, query_embed, TGTh);

    // ---- encoder ----
    for (int i = 0; i < 3; i++) {
        gemm_bf16(Xh, h_enc_vp + (size_t)i * 65536, enc_vp_b + i * 256, Vh, ME, 256, 256, 0, 1, stream);
        hipLaunchKernelGGL(add_pos_kernel, dim3((ME * 64 + 255) / 256), dim3(256), 0, stream,
                           Xh, POSb, Qh);
        gemm_bf16(Qh, h_enc_offaw + (size_t)i * 73728, enc_oab + i * 288, OAf, ME, 288, 256, 0, 0, stream);
        hipLaunchKernelGGL(msda_kernel, dim3((ME + MROWS - 1) / MROWS), dim3(256), 0, stream,
                           Vh, OAf, REFEb, OUTh, 0, ME);
        gemm_bf16(OUTh, h_enc_op + (size_t)i * 65536, enc_op_b + i * 256, Yh, ME, 256, 256, 0, 1, stream);
        hipLaunchKernelGGL(ln_res_kernel, dim3((ME + 3) / 4), dim3(256), 0, stream,
                           Xh, Yh, enc_ln1_g + i * 256, enc_ln1_b + i * 256, Xh, (float*)nullptr, ME);
        gemm_bf16(Xh, h_enc_fc1 + (size_t)i * 262144, enc_fc1_b + i * 1024, HIDh, ME, 1024, 256, 1, 1, stream);
        gemm_bf16(HIDh, h_enc_fc2 + (size_t)i * 262144, enc_fc2_b + i * 256, Yh, ME, 256, 1024, 0, 1, stream);
        hipLaunchKernelGGL(ln_res_kernel, dim3((ME + 3) / 4), dim3(256), 0, stream,
                           Xh, Yh, enc_ln2_g + i * 256, enc_ln2_b + i * 256, Xh, (float*)nullptr, ME);
    }

    // ---- decoder ----
    for (int i = 0; i < 3; i++) {
        gemm_bf16(TGTh, h_sa_in + (size_t)i * 196608, sa_in_b + i * 768, QKVh, MD, 768, 256, 0, 1, stream);
        hipLaunchKernelGGL(mha_kernel, dim3((MD * 8 + 255) / 256), dim3(256), 0, stream,
                           QKVh, SOh, MD / 8);
        gemm_bf16(SOh, h_sa_out + (size_t)i * 65536, sa_out_b + i * 256, Yh, MD, 256, 256, 0, 1, stream);
        hipLaunchKernelGGL(ln_res_kernel, dim3((MD + 3) / 4), dim3(256), 0, stream,
                           TGTh, Yh, dec_ln2_g + i * 256, dec_ln2_b + i * 256, TGTh, (float*)nullptr, MD);
        gemm_bf16(Xh, h_dec_vp + (size_t)i * 65536, dec_vp_b + i * 256, Vh, ME, 256, 256, 0, 1, stream);
        gemm_bf16(TGTh, h_dec_offaw + (size_t)i * 73728, dec_oab + i * 288, OAf, MD, 288, 256, 0, 0, stream);
        hipLaunchKernelGGL(msda_kernel, dim3((MD + MROWS - 1) / MROWS), dim3(256), 0, stream,
                           Vh, OAf, REFDb, OUTh, 1, MD);
        gemm_bf16(OUTh, h_dec_op + (size_t)i * 65536, dec_op_b + i * 256, Yh, MD, 256, 256, 0, 1, stream);
        hipLaunchKernelGGL(ln_res_kernel, dim3((MD + 3) / 4), dim3(256), 0, stream,
                           TGTh, Yh, dec_ln1_g + i * 256, dec_ln1_b + i * 256, TGTh, (float*)nullptr, MD);
        gemm_bf16(TGTh, h_dec_fc1 + (size_t)i * 262144, dec_fc1_b + i * 1024, HIDh, MD, 1024, 256, 1, 1, stream);
        gemm_bf16(HIDh, h_dec_fc2 + (size_t)i * 262144, dec_fc2_b + i * 256, Yh, MD, 256, 1024, 0, 1, stream);
        float* outf = (i == 2) ? (float*)d_out : nullptr;
        hipLaunchKernelGGL(ln_res_kernel, dim3((MD + 3) / 4), dim3(256), 0, stream,
                           TGTh, Yh, dec_ln3_g + i * 256, dec_ln3_b + i * 256, TGTh, outf, MD);
    }
}